// Round 22
// baseline (276.649 us; speedup 1.0000x reference)
//
#include <hip/hip_runtime.h>
#include <hip/hip_bf16.h>

// dims (fixed per reference)
#define L_   2048
#define H_   2048
#define I_   2048
#define NH_  16
#define HPH_ 128
#define NS_  64
#define R_   128
#define NCH_ 64     // chunks
#define CT_  32     // steps per chunk
#define LOG2E 1.4426950408889634f

typedef __attribute__((ext_vector_type(8))) short s16x8;
typedef __attribute__((ext_vector_type(4))) float f32x4;

__device__ __forceinline__ short f2bf(float x) {
  unsigned u = __builtin_bit_cast(unsigned, x);
  u += 0x7fff + ((u >> 16) & 1);   // round-to-nearest-even
  return (short)(u >> 16);
}
__device__ __forceinline__ float bf2f(unsigned short v) {
  return __builtin_bit_cast(float, (unsigned)v << 16);
}

// native v_exp_f32 (2^x), no libm guard code
__device__ __forceinline__ float ex2(float x) {
  return __builtin_amdgcn_exp2f(x);
}

// async global->LDS, 16B per lane; LDS dest = wave-uniform base + lane*16
__device__ __forceinline__ void gll16(const void* g, void* l) {
  __builtin_amdgcn_global_load_lds(
      (__attribute__((address_space(1))) void*)(void*)g,
      (__attribute__((address_space(3))) void*)l, 16, 0, 0);
}

// ---- pack weight W[K][N] (f32 row-major) -> Wp[(k>>3)][n][k%8] bf16 ----
__global__ __launch_bounds__(256) void pack_w(const float* __restrict__ W,
                                              short* __restrict__ Wp,
                                              int KN, int logN) {
  int idx = blockIdx.x * 256 + threadIdx.x;
  if (idx >= KN) return;
  int k = idx >> logN;
  int n = idx & ((1 << logN) - 1);
  Wp[((size_t)(k >> 3) << (logN + 3)) + ((size_t)n << 3) + (k & 7)] = f2bf(W[idx]);
}

__global__ __launch_bounds__(256) void cast_bf(const float* __restrict__ X,
                                               short* __restrict__ Xb, int nElem) {
  int idx = blockIdx.x * 256 + threadIdx.x;
  if (idx < nElem) Xb[idx] = f2bf(X[idx]);
}

// ---- staged bf16 MFMA GEMM (m97 structure) + bijective XCD swizzle ----
template<int BM>
__global__ __launch_bounds__(256) void gemm_st(const short* __restrict__ A,
                                               const short* __restrict__ Bp,
                                               float* __restrict__ C,
                                               int M, int N, int K) {
  constexpr int MI = BM / 32;                 // m-fragments per wave
  __shared__ short sA[BM * 64];               // [BM][64] bf16, swizzled
  __shared__ short sB[8 * 128 * 8];           // [kg][n][8] bf16, linear
  int tid = threadIdx.x;
  int lane = tid & 63, wid = tid >> 6;
  int wr = wid >> 1, wc = wid & 1;
  int l15 = lane & 15, l16 = lane >> 4;

  // XCD-aware bijective swizzle (nwg % 8 == 0 for all our grids)
  int nwg = gridDim.x * gridDim.y;
  int lin = blockIdx.x + gridDim.x * blockIdx.y;
  int cpx = nwg >> 3;
  int swz = (lin & 7) * cpx + (lin >> 3);
  int bm = (swz % gridDim.x) * BM, bn = (swz / gridDim.x) * 128;

  f32x4 acc[MI][4] = {};

  int arow = lane >> 3;                       // row within 8-row group
  int acolb = ((lane & 7) ^ arow) * 16;       // inverse-swizzled source byte
  const char* Ag = (const char*)(A + (size_t)bm * K) + acolb;
  const char* Bg = (const char*)(Bp + (size_t)bn * 8);

  for (int k0 = 0; k0 < K; k0 += 64) {
    __syncthreads();
#pragma unroll
    for (int q = 0; q < BM / 32; ++q) {       // stage A: 1KB per inst
      int rbase = (q * 4 + wid) * 8;
      gll16(Ag + ((size_t)(rbase + arow) * K + k0) * 2,
            (char*)sA + rbase * 128);
    }
#pragma unroll
    for (int q = 0; q < 4; ++q) {             // stage B: 1KB per inst
      int c = q * 4 + wid;
      int kg = c >> 1, nh = (c & 1) * 64;
      gll16(Bg + ((size_t)(k0 / 8 + kg) * N * 8 + (size_t)(nh + lane) * 8) * 2,
            (char*)sB + kg * 2048 + nh * 16);
    }
    __syncthreads();

#pragma unroll
    for (int kk = 0; kk < 64; kk += 32) {
      s16x8 a[MI], b[4];
#pragma unroll
      for (int mi = 0; mi < MI; ++mi) {
        int row = wr * (BM / 2) + mi * 16 + l15;
        int kb = ((kk + l16 * 8) * 2) ^ ((row & 7) << 4);   // swizzled read
        a[mi] = *(const s16x8*)((const char*)sA + row * 128 + kb);
      }
#pragma unroll
      for (int ni = 0; ni < 4; ++ni) {
        int n = wc * 64 + ni * 16 + l15;
        int kg = (kk >> 3) + l16;
        b[ni] = *(const s16x8*)((const char*)sB + (kg * 128 + n) * 16);
      }
#pragma unroll
      for (int mi = 0; mi < MI; ++mi)
#pragma unroll
        for (int ni = 0; ni < 4; ++ni)
          acc[mi][ni] = __builtin_amdgcn_mfma_f32_16x16x32_bf16(a[mi], b[ni], acc[mi][ni], 0, 0, 0);
    }
  }
#pragma unroll
  for (int mi = 0; mi < MI; ++mi) {
    int row0 = bm + wr * (BM / 2) + mi * 16 + l16 * 4;
#pragma unroll
    for (int ni = 0; ni < 4; ++ni) {
      int col = bn + wc * 64 + ni * 16 + l15;
#pragma unroll
      for (int r = 0; r < 4; ++r)
        C[(size_t)(row0 + r) * N + col] = acc[mi][ni][r];
    }
  }
}

// ---- causal depthwise conv (K=4) + SiLU -> bf16; silu(gate) -> bf16 ----
__global__ __launch_bounds__(256) void conv_silu(const float* __restrict__ proj,
                                                 const float* __restrict__ convw,
                                                 short* __restrict__ hsb,
                                                 short* __restrict__ gate_b) {
  int idx = blockIdx.x * 256 + threadIdx.x;   // over L_*I_
  int t = idx >> 11, i = idx & (I_ - 1);
  int col = ((i >> 7) << 8) + 128 + (i & 127);  // head*256 + 128 + (i%128)
  float4 cw = *(const float4*)(convw + i * 4);
  const float* p = proj + (size_t)t * (2 * I_) + col;
  float acc = cw.w * p[0];
  if (t >= 1) acc += cw.z * p[-(2 * I_)];
  if (t >= 2) acc += cw.y * p[-(2 * I_) * 2];
  if (t >= 3) acc += cw.x * p[-(2 * I_) * 3];
  float h = acc / (1.f + __expf(-acc));   // silu
  hsb[idx] = f2bf(h);
  float g = p[-128];                      // gate element for channel i
  gate_b[idx] = f2bf(g / (1.f + __expf(-g)));   // silu(gate)
}

// ---- RMSNorms (B, C, ts) + dt = ts@dt_proj + softplus(dt + bias) ----
__global__ __launch_bounds__(256) void norm_dt(const float* __restrict__ sp,
                                               const float* __restrict__ Bw,
                                               const float* __restrict__ Cw,
                                               const float* __restrict__ dtw,
                                               const float* __restrict__ Wdt,
                                               const float* __restrict__ bias,
                                               float* __restrict__ Bo,
                                               float* __restrict__ Co,
                                               float* __restrict__ delta) {
  int lane = threadIdx.x & 63, w = threadIdx.x >> 6;
  int t = blockIdx.x * 4 + w;
  const float* row = sp + (size_t)t * 256;
  float v0 = row[lane], v1 = row[64 + lane], v2 = row[128 + lane], v3 = row[192 + lane];
  float sB = v0 * v0, sC = v1 * v1, sT = v2 * v2 + v3 * v3;
#pragma unroll
  for (int off = 32; off; off >>= 1) {
    sB += __shfl_xor(sB, off);
    sC += __shfl_xor(sC, off);
    sT += __shfl_xor(sT, off);
  }
  float rB = rsqrtf(sB * (1.f / 64) + 1e-6f);
  float rC = rsqrtf(sC * (1.f / 64) + 1e-6f);
  float rT = rsqrtf(sT * (1.f / 128) + 1e-6f);
  Bo[t * 64 + lane] = v0 * rB * Bw[lane];
  Co[t * 64 + lane] = v1 * rC * Cw[lane];
  float t2 = v2 * rT * dtw[lane], t3 = v3 * rT * dtw[64 + lane];
  float p[NH_];
  const float* w0 = Wdt + lane * NH_;
  const float* w1 = Wdt + (64 + lane) * NH_;
#pragma unroll
  for (int h = 0; h < NH_; ++h) p[h] = t2 * w0[h] + t3 * w1[h];
#pragma unroll
  for (int off = 32; off; off >>= 1)
#pragma unroll
    for (int h = 0; h < NH_; ++h) p[h] += __shfl_xor(p[h], off);
  if (lane == 0) {
#pragma unroll
    for (int h = 0; h < NH_; ++h) {
      float x = p[h] + bias[h];
      delta[t * NH_ + h] = (x > 20.f) ? x : log1pf(__expf(x));
    }
  }
}

// ---- per-(chunk, head) delta sums ----
__global__ __launch_bounds__(512) void chunk_sums(const float* __restrict__ delta,
                                                  float* __restrict__ sumd) {
  int t = blockIdx.x * 512 + threadIdx.x;   // NCH_*16 = 1024
  int c = t >> 4, h = t & 15;
  float s = 0.f;
  const float* p = delta + (size_t)c * CT_ * NH_ + h;
#pragma unroll 8
  for (int j = 0; j < CT_; ++j) s += p[(size_t)j * NH_];
  sumd[t] = s;
}

// ======================= chunked selective scan ==========================
// r17-verified 4ch x 16n layout; A pre-scaled by log2e; native v_exp; st in
// bf16.  NEW: u-tile cooperatively staged into LDS (f32 [32][256]) — removes
// 4 scalar global loads per thread-step (the exposed-latency source).
__device__ __forceinline__ float rdlane(float v, int l) {
  return __builtin_bit_cast(float, __builtin_amdgcn_readlane(__builtin_bit_cast(int, v), l));
}

// ---- phase 1: local scan from zero (state only) ----
__global__ __launch_bounds__(256) void scan1(const short* __restrict__ hs,     // [L+1, I] bf16
                                             const float* __restrict__ Bm,     // [L, N]
                                             const float* __restrict__ delta,  // [L, NH]
                                             const float* __restrict__ A,      // [I, N]
                                             short* __restrict__ st) {         // [NCH][N][I] bf16
  __shared__ float sB[CT_ * 64];              // 8 KB
  __shared__ float su[CT_ * 256];             // 32 KB
  int tid = threadIdx.x;
  int lane = tid & 63, wv = tid >> 6;
  int c0b = blockIdx.x * 256;
  int c0w = c0b + wv * 64;
  int c = lane & 15, q = lane >> 4;
  int chunk = blockIdx.y;
  int t0 = chunk * CT_;
  int head = c0w >> 7;
  int nb = q * 16;
  int ch0 = c0w + c;
  int lu = wv * 64 + c;                       // local u index base

  { const float4* B4 = (const float4*)(Bm + (size_t)t0 * 64);
    float4* S4 = (float4*)sB;
    S4[tid] = B4[tid];
    S4[256 + tid] = B4[256 + tid]; }
  // stage u tile [32][256] bf16 -> f32 (4 coalesced short8 loads/thread)
  { int cc = tid & 31, tt0 = tid >> 5;
#pragma unroll
    for (int r = 0; r < 4; ++r) {
      int tt = r * 8 + tt0;
      s16x8 v = *(const s16x8*)(hs + (size_t)(t0 + tt) * I_ + c0b + cc * 8);
      float* dst = &su[tt * 256 + cc * 8];
      float4 lo = {bf2f((unsigned short)v[0]), bf2f((unsigned short)v[1]),
                   bf2f((unsigned short)v[2]), bf2f((unsigned short)v[3])};
      float4 hi = {bf2f((unsigned short)v[4]), bf2f((unsigned short)v[5]),
                   bf2f((unsigned short)v[6]), bf2f((unsigned short)v[7])};
      *(float4*)dst = lo;
      *(float4*)(dst + 4) = hi;
    } }
  float d_r = delta[(size_t)(t0 + (lane & 31)) * NH_ + head];

  float aL[4][16], s[4][16];
#pragma unroll
  for (int j = 0; j < 4; ++j) {
    const float* Ap = A + (size_t)(ch0 + 16 * j) * 64 + nb;
#pragma unroll
    for (int k4 = 0; k4 < 4; ++k4) {
      float4 av = *(const float4*)(Ap + k4 * 4);
      aL[j][k4*4+0] = av.x * LOG2E; aL[j][k4*4+1] = av.y * LOG2E;
      aL[j][k4*4+2] = av.z * LOG2E; aL[j][k4*4+3] = av.w * LOG2E;
    }
#pragma unroll
    for (int k = 0; k < 16; ++k) s[j][k] = 0.f;
  }
  __syncthreads();

#pragma unroll 1
  for (int t = 0; t < CT_; ++t) {
    float dlt = rdlane(d_r, t);
    const float* ut = &su[t * 256 + lu];
    float du0 = dlt * ut[0], du1 = dlt * ut[16], du2 = dlt * ut[32], du3 = dlt * ut[48];
    const float* bt = &sB[t * 64 + nb];
#pragma unroll
    for (int k4 = 0; k4 < 4; ++k4) {
      float4 b4 = *(const float4*)&bt[k4 * 4];
#pragma unroll
      for (int e = 0; e < 4; ++e) {
        int k = k4 * 4 + e; float bb = (&b4.x)[e];
        s[0][k] = s[0][k] * ex2(dlt * aL[0][k]) + du0 * bb;
        s[1][k] = s[1][k] * ex2(dlt * aL[1][k]) + du1 * bb;
        s[2][k] = s[2][k] * ex2(dlt * aL[2][k]) + du2 * bb;
        s[3][k] = s[3][k] * ex2(dlt * aL[3][k]) + du3 * bb;
      }
    }
  }
  size_t base = ((size_t)chunk << 17) + ch0;
#pragma unroll
  for (int j = 0; j < 4; ++j)
#pragma unroll
    for (int k = 0; k < 16; ++k)
      st[base + ((size_t)(nb + k) << 11) + 16 * j] = f2bf(s[j][k]);
}

// ---- phase 2: register-blocked sequential combine (loads all chunks) ----
__global__ __launch_bounds__(256) void scan2(const float* __restrict__ A,
                                             const float* __restrict__ sumd,  // [NCH*16]
                                             short* __restrict__ st) {        // [NCH][N][I] bf16
  int g = blockIdx.x * 256 + threadIdx.x;    // over N*I = 131072
  int i = g & (I_ - 1), n = g >> 11;
  int h = i >> 7;
  float aL = A[((size_t)i << 6) + n] * LOG2E;
  float loc[NCH_];
#pragma unroll
  for (int c = 0; c < NCH_; ++c)
    loc[c] = bf2f((unsigned short)st[((size_t)c << 17) + g]);
  float s = 0.f;
#pragma unroll
  for (int c = 0; c < NCH_; ++c) {
    float gfac = ex2(aL * sumd[c * 16 + h]);
    float nxt = s * gfac + loc[c];
    st[((size_t)c << 17) + g] = f2bf(s);      // incoming state for chunk c
    s = nxt;
  }
}

// ---- phase 3: recompute with incoming state + y + fused epilogue ----
__global__ __launch_bounds__(256) void scan3(const short* __restrict__ hs,     // [L+1, I] bf16
                                             const float* __restrict__ Bm,     // [L, N]
                                             const float* __restrict__ Cm,     // [L, N]
                                             const float* __restrict__ delta,  // [L, NH]
                                             const float* __restrict__ A,      // [I, N]
                                             const float* __restrict__ Dv,     // [I]
                                             const short* __restrict__ gate_b, // [L, I] bf16
                                             const short* __restrict__ st,     // [NCH][N][I] bf16
                                             short* __restrict__ ybf) {        // [L, I] bf16
  __shared__ float sB[CT_ * 64], sC[CT_ * 64];   // 16 KB
  __shared__ float su[CT_ * 256];                // 32 KB
  int tid = threadIdx.x;
  int lane = tid & 63, wv = tid >> 6;
  int c0b = blockIdx.x * 256;
  int c0w = c0b + wv * 64;
  int c = lane & 15, q = lane >> 4;
  int chunk = blockIdx.y;
  int t0 = chunk * CT_;
  int head = c0w >> 7;
  int nb = q * 16;
  int ch0 = c0w + c;
  int lu = wv * 64 + c;

  { const float4* B4 = (const float4*)(Bm + (size_t)t0 * 64);
    const float4* C4 = (const float4*)(Cm + (size_t)t0 * 64);
    float4* SB4 = (float4*)sB;
    float4* SC4 = (float4*)sC;
    SB4[tid] = B4[tid];       SB4[256 + tid] = B4[256 + tid];
    SC4[tid] = C4[tid];       SC4[256 + tid] = C4[256 + tid]; }
  // stage u tile [32][256] bf16 -> f32
  { int cc = tid & 31, tt0 = tid >> 5;
#pragma unroll
    for (int r = 0; r < 4; ++r) {
      int tt = r * 8 + tt0;
      s16x8 v = *(const s16x8*)(hs + (size_t)(t0 + tt) * I_ + c0b + cc * 8);
      float* dst = &su[tt * 256 + cc * 8];
      float4 lo = {bf2f((unsigned short)v[0]), bf2f((unsigned short)v[1]),
                   bf2f((unsigned short)v[2]), bf2f((unsigned short)v[3])};
      float4 hi = {bf2f((unsigned short)v[4]), bf2f((unsigned short)v[5]),
                   bf2f((unsigned short)v[6]), bf2f((unsigned short)v[7])};
      *(float4*)dst = lo;
      *(float4*)(dst + 4) = hi;
    } }
  float d_r = delta[(size_t)(t0 + (lane & 31)) * NH_ + head];
  float D_own = Dv[c0w + lane];

  float aL[4][16], s[4][16];
#pragma unroll
  for (int j = 0; j < 4; ++j) {
    const float* Ap = A + (size_t)(ch0 + 16 * j) * 64 + nb;
#pragma unroll
    for (int k4 = 0; k4 < 4; ++k4) {
      float4 av = *(const float4*)(Ap + k4 * 4);
      aL[j][k4*4+0] = av.x * LOG2E; aL[j][k4*4+1] = av.y * LOG2E;
      aL[j][k4*4+2] = av.z * LOG2E; aL[j][k4*4+3] = av.w * LOG2E;
    }
  }
  { size_t base = ((size_t)chunk << 17) + ch0;
#pragma unroll
    for (int j = 0; j < 4; ++j)
#pragma unroll
      for (int k = 0; k < 16; ++k)
        s[j][k] = bf2f((unsigned short)st[base + ((size_t)(nb + k) << 11) + 16 * j]);
  }
  __syncthreads();

  const short* gp = gate_b + (size_t)t0 * I_ + c0w + lane;
  short* yp = ybf + (size_t)t0 * I_ + c0w + lane;
  bool b4f = lane & 16, b5f = lane & 32;
#pragma unroll 1
  for (int t = 0; t < CT_; ++t) {
    float gv = bf2f((unsigned short)gp[(size_t)t * I_]);
    float dlt = rdlane(d_r, t);
    const float* ut = &su[t * 256 + lu];
    float du0 = dlt * ut[0], du1 = dlt * ut[16], du2 = dlt * ut[32], du3 = dlt * ut[48];
    float u_own = su[t * 256 + wv * 64 + lane];
    const float* bt = &sB[t * 64 + nb];
    const float* ct = &sC[t * 64 + nb];
    float p0 = 0.f, p1 = 0.f, p2 = 0.f, p3 = 0.f;
#pragma unroll
    for (int k4 = 0; k4 < 4; ++k4) {
      float4 b4 = *(const float4*)&bt[k4 * 4];
      float4 c4 = *(const float4*)&ct[k4 * 4];
#pragma unroll
      for (int e = 0; e < 4; ++e) {
        int k = k4 * 4 + e;
        float bb = (&b4.x)[e], cc = (&c4.x)[e];
        s[0][k] = s[0][k] * ex2(dlt * aL[0][k]) + du0 * bb;  p0 += s[0][k] * cc;
        s[1][k] = s[1][k] * ex2(dlt * aL[1][k]) + du1 * bb;  p1 += s[1][k] * cc;
        s[2][k] = s[2][k] * ex2(dlt * aL[2][k]) + du2 * bb;  p2 += s[2][k] * cc;
        s[3][k] = s[3][k] * ex2(dlt * aL[3][k]) + du3 * bb;  p3 += s[3][k] * cc;
      }
    }
    // reduce over n-quarters; lane (q,c) ends with y for channel c0w+lane
    float sa = b5f ? p0 : p2;
    float sb = b5f ? p1 : p3;
    float qa = (b5f ? p2 : p0) + __shfl_xor(sa, 32);
    float qb = (b5f ? p3 : p1) + __shfl_xor(sb, 32);
    float sc = b4f ? qa : qb;
    float y  = (b4f ? qb : qa) + __shfl_xor(sc, 16);
    y += D_own * u_own;
    yp[(size_t)t * I_] = f2bf(y * gv);
  }
}

extern "C" void kernel_launch(void* const* d_in, const int* in_sizes, int n_in,
                              void* d_out, int out_size, void* d_ws, size_t ws_size,
                              hipStream_t stream) {
  const float* hidden  = (const float*)d_in[0];
  const float* inproj  = (const float*)d_in[1];
  const float* convw   = (const float*)d_in[2];
  const float* bcdtw   = (const float*)d_in[3];
  const float* dtnw    = (const float*)d_in[4];
  const float* Bnw     = (const float*)d_in[5];
  const float* Cnw     = (const float*)d_in[6];
  const float* dtpw    = (const float*)d_in[7];
  const float* dtbias  = (const float*)d_in[8];
  const float* Amat    = (const float*)d_in[9];
  const float* Dvec    = (const float*)d_in[10];
  const float* outproj = (const float*)d_in[11];
  float* out = (float*)d_out;

  char* ws = (char*)d_ws;
  short* inproj_p  = (short*)ws; ws += (size_t)H_ * 2 * I_ * 2;   // 16 MB
  short* bcdt_p    = (short*)ws; ws += (size_t)I_ * 256 * 2;
  short* outproj_p = (short*)ws; ws += (size_t)I_ * H_ * 2;
  short* hid_b     = (short*)ws; ws += (size_t)L_ * H_ * 2;
  float* proj      = (float*)ws; ws += (size_t)L_ * 2 * I_ * 4;   // 32 MB
  short* hs_b      = (short*)ws; ws += (size_t)(L_ + 1) * I_ * 2; // +1 pad row
  short* gate_b    = (short*)ws; ws += (size_t)L_ * I_ * 2;       // 8 MB
  float* ssmp      = (float*)ws; ws += (size_t)L_ * 256 * 4;
  float* Bmat      = (float*)ws; ws += (size_t)L_ * NS_ * 4;
  float* Cmat      = (float*)ws; ws += (size_t)L_ * NS_ * 4;
  float* delta     = (float*)ws; ws += (size_t)L_ * NH_ * 4;
  short* y_b       = (short*)ws; ws += (size_t)L_ * I_ * 2;
  float* sumd      = (float*)ws; ws += NCH_ * 16 * 4;
  // chunk-state buffer [NCH][N][I] bf16 = 16 MB: aliases proj, dead after
  // conv_silu (gate extracted to gate_b).  Stream-ordered each launch.
  short* sstate    = (short*)proj;

  pack_w<<<(H_ * 2 * I_ + 255) / 256, 256, 0, stream>>>(inproj, inproj_p, H_ * 2 * I_, 12);
  pack_w<<<(I_ * 256 + 255) / 256, 256, 0, stream>>>(bcdtw, bcdt_p, I_ * 256, 8);
  pack_w<<<(I_ * H_ + 255) / 256, 256, 0, stream>>>(outproj, outproj_p, I_ * H_, 11);
  cast_bf<<<(L_ * H_ + 255) / 256, 256, 0, stream>>>(hidden, hid_b, L_ * H_);

  gemm_st<128><<<dim3(L_ / 128, (2 * I_) / 128), 256, 0, stream>>>(hid_b, inproj_p, proj, L_, 2 * I_, H_);
  conv_silu<<<(L_ * I_) / 256, 256, 0, stream>>>(proj, convw, hs_b, gate_b);
  gemm_st<64><<<dim3(L_ / 64, 256 / 128), 256, 0, stream>>>(hs_b, bcdt_p, ssmp, L_, 256, I_);
  norm_dt<<<L_ / 4, 256, 0, stream>>>(ssmp, Bnw, Cnw, dtnw, dtpw, dtbias, Bmat, Cmat, delta);

  chunk_sums<<<(NCH_ * 16) / 512, 512, 0, stream>>>(delta, sumd);
  scan1<<<dim3(I_ / 256, NCH_), 256, 0, stream>>>(hs_b, Bmat, delta, Amat, sstate);
  scan2<<<(I_ * 64) / 256, 256, 0, stream>>>(Amat, sumd, sstate);
  scan3<<<dim3(I_ / 256, NCH_), 256, 0, stream>>>(hs_b, Bmat, Cmat, delta, Amat, Dvec, gate_b, sstate, y_b);

  gemm_st<64><<<dim3(L_ / 64, H_ / 128), 256, 0, stream>>>(y_b, outproj_p, out, L_, H_, I_);
}

// Round 23
// 264.650 us; speedup vs baseline: 1.0453x; 1.0453x over previous
//
#include <hip/hip_runtime.h>
#include <hip/hip_bf16.h>

// dims (fixed per reference)
#define L_   2048
#define H_   2048
#define I_   2048
#define NH_  16
#define HPH_ 128
#define NS_  64
#define R_   128
#define NCH_ 64     // chunks
#define CT_  32     // steps per chunk
#define LOG2E 1.4426950408889634f

typedef __attribute__((ext_vector_type(8))) short s16x8;
typedef __attribute__((ext_vector_type(4))) float f32x4;

__device__ __forceinline__ short f2bf(float x) {
  unsigned u = __builtin_bit_cast(unsigned, x);
  u += 0x7fff + ((u >> 16) & 1);   // round-to-nearest-even
  return (short)(u >> 16);
}
__device__ __forceinline__ float bf2f(unsigned short v) {
  return __builtin_bit_cast(float, (unsigned)v << 16);
}

// native v_exp_f32 (2^x), no libm guard code
__device__ __forceinline__ float ex2(float x) {
  return __builtin_amdgcn_exp2f(x);
}

// async global->LDS, 16B per lane; LDS dest = wave-uniform base + lane*16
__device__ __forceinline__ void gll16(const void* g, void* l) {
  __builtin_amdgcn_global_load_lds(
      (__attribute__((address_space(1))) void*)(void*)g,
      (__attribute__((address_space(3))) void*)l, 16, 0, 0);
}

// ---- pack weight W[K][N] (f32 row-major) -> Wp[(k>>3)][n][k%8] bf16 ----
// thread = (k-group, n): 8 coalesced strided reads + ONE contiguous short8
// write (16B/lane -> 1KB/wave, no write amplification).
__global__ __launch_bounds__(256) void pack_w8(const float* __restrict__ W,
                                               short* __restrict__ Wp,
                                               int KN8, int logN) {
  int idx = blockIdx.x * 256 + threadIdx.x;   // over K*N/8
  if (idx >= KN8) return;
  int kg = idx >> logN;
  int n = idx & ((1 << logN) - 1);
  const float* src = W + ((size_t)(kg * 8) << logN) + n;
  s16x8 v;
#pragma unroll
  for (int j = 0; j < 8; ++j) v[j] = f2bf(src[(size_t)j << logN]);
  *(s16x8*)(Wp + ((size_t)kg << (logN + 3)) + ((size_t)n << 3)) = v;
}

__global__ __launch_bounds__(256) void cast_bf(const float* __restrict__ X,
                                               short* __restrict__ Xb, int nElem) {
  int idx = blockIdx.x * 256 + threadIdx.x;
  if (idx < nElem) Xb[idx] = f2bf(X[idx]);
}

// ---- staged bf16 MFMA GEMM (m97 structure) + bijective XCD swizzle ----
template<int BM>
__global__ __launch_bounds__(256) void gemm_st(const short* __restrict__ A,
                                               const short* __restrict__ Bp,
                                               float* __restrict__ C,
                                               int M, int N, int K) {
  constexpr int MI = BM / 32;                 // m-fragments per wave
  __shared__ short sA[BM * 64];               // [BM][64] bf16, swizzled
  __shared__ short sB[8 * 128 * 8];           // [kg][n][8] bf16, linear
  int tid = threadIdx.x;
  int lane = tid & 63, wid = tid >> 6;
  int wr = wid >> 1, wc = wid & 1;
  int l15 = lane & 15, l16 = lane >> 4;

  // XCD-aware bijective swizzle (nwg % 8 == 0 for all our grids)
  int nwg = gridDim.x * gridDim.y;
  int lin = blockIdx.x + gridDim.x * blockIdx.y;
  int cpx = nwg >> 3;
  int swz = (lin & 7) * cpx + (lin >> 3);
  int bm = (swz % gridDim.x) * BM, bn = (swz / gridDim.x) * 128;

  f32x4 acc[MI][4] = {};

  int arow = lane >> 3;                       // row within 8-row group
  int acolb = ((lane & 7) ^ arow) * 16;       // inverse-swizzled source byte
  const char* Ag = (const char*)(A + (size_t)bm * K) + acolb;
  const char* Bg = (const char*)(Bp + (size_t)bn * 8);

  for (int k0 = 0; k0 < K; k0 += 64) {
    __syncthreads();
#pragma unroll
    for (int q = 0; q < BM / 32; ++q) {       // stage A: 1KB per inst
      int rbase = (q * 4 + wid) * 8;
      gll16(Ag + ((size_t)(rbase + arow) * K + k0) * 2,
            (char*)sA + rbase * 128);
    }
#pragma unroll
    for (int q = 0; q < 4; ++q) {             // stage B: 1KB per inst
      int c = q * 4 + wid;
      int kg = c >> 1, nh = (c & 1) * 64;
      gll16(Bg + ((size_t)(k0 / 8 + kg) * N * 8 + (size_t)(nh + lane) * 8) * 2,
            (char*)sB + kg * 2048 + nh * 16);
    }
    __syncthreads();

#pragma unroll
    for (int kk = 0; kk < 64; kk += 32) {
      s16x8 a[MI], b[4];
#pragma unroll
      for (int mi = 0; mi < MI; ++mi) {
        int row = wr * (BM / 2) + mi * 16 + l15;
        int kb = ((kk + l16 * 8) * 2) ^ ((row & 7) << 4);   // swizzled read
        a[mi] = *(const s16x8*)((const char*)sA + row * 128 + kb);
      }
#pragma unroll
      for (int ni = 0; ni < 4; ++ni) {
        int n = wc * 64 + ni * 16 + l15;
        int kg = (kk >> 3) + l16;
        b[ni] = *(const s16x8*)((const char*)sB + (kg * 128 + n) * 16);
      }
#pragma unroll
      for (int mi = 0; mi < MI; ++mi)
#pragma unroll
        for (int ni = 0; ni < 4; ++ni)
          acc[mi][ni] = __builtin_amdgcn_mfma_f32_16x16x32_bf16(a[mi], b[ni], acc[mi][ni], 0, 0, 0);
    }
  }
#pragma unroll
  for (int mi = 0; mi < MI; ++mi) {
    int row0 = bm + wr * (BM / 2) + mi * 16 + l16 * 4;
#pragma unroll
    for (int ni = 0; ni < 4; ++ni) {
      int col = bn + wc * 64 + ni * 16 + l15;
#pragma unroll
      for (int r = 0; r < 4; ++r)
        C[(size_t)(row0 + r) * N + col] = acc[mi][ni][r];
    }
  }
}

// ---- causal depthwise conv (K=4) + SiLU -> bf16; silu(gate) -> bf16 ----
__global__ __launch_bounds__(256) void conv_silu(const float* __restrict__ proj,
                                                 const float* __restrict__ convw,
                                                 short* __restrict__ hsb,
                                                 short* __restrict__ gate_b) {
  int idx = blockIdx.x * 256 + threadIdx.x;   // over L_*I_
  int t = idx >> 11, i = idx & (I_ - 1);
  int col = ((i >> 7) << 8) + 128 + (i & 127);  // head*256 + 128 + (i%128)
  float4 cw = *(const float4*)(convw + i * 4);
  const float* p = proj + (size_t)t * (2 * I_) + col;
  float acc = cw.w * p[0];
  if (t >= 1) acc += cw.z * p[-(2 * I_)];
  if (t >= 2) acc += cw.y * p[-(2 * I_) * 2];
  if (t >= 3) acc += cw.x * p[-(2 * I_) * 3];
  float h = acc / (1.f + __expf(-acc));   // silu
  hsb[idx] = f2bf(h);
  float g = p[-128];                      // gate element for channel i
  gate_b[idx] = f2bf(g / (1.f + __expf(-g)));   // silu(gate)
}

// ---- RMSNorms (B, C, ts) + dt = ts@dt_proj + softplus(dt + bias) ----
__global__ __launch_bounds__(256) void norm_dt(const float* __restrict__ sp,
                                               const float* __restrict__ Bw,
                                               const float* __restrict__ Cw,
                                               const float* __restrict__ dtw,
                                               const float* __restrict__ Wdt,
                                               const float* __restrict__ bias,
                                               float* __restrict__ Bo,
                                               float* __restrict__ Co,
                                               float* __restrict__ delta) {
  int lane = threadIdx.x & 63, w = threadIdx.x >> 6;
  int t = blockIdx.x * 4 + w;
  const float* row = sp + (size_t)t * 256;
  float v0 = row[lane], v1 = row[64 + lane], v2 = row[128 + lane], v3 = row[192 + lane];
  float sB = v0 * v0, sC = v1 * v1, sT = v2 * v2 + v3 * v3;
#pragma unroll
  for (int off = 32; off; off >>= 1) {
    sB += __shfl_xor(sB, off);
    sC += __shfl_xor(sC, off);
    sT += __shfl_xor(sT, off);
  }
  float rB = rsqrtf(sB * (1.f / 64) + 1e-6f);
  float rC = rsqrtf(sC * (1.f / 64) + 1e-6f);
  float rT = rsqrtf(sT * (1.f / 128) + 1e-6f);
  Bo[t * 64 + lane] = v0 * rB * Bw[lane];
  Co[t * 64 + lane] = v1 * rC * Cw[lane];
  float t2 = v2 * rT * dtw[lane], t3 = v3 * rT * dtw[64 + lane];
  float p[NH_];
  const float* w0 = Wdt + lane * NH_;
  const float* w1 = Wdt + (64 + lane) * NH_;
#pragma unroll
  for (int h = 0; h < NH_; ++h) p[h] = t2 * w0[h] + t3 * w1[h];
#pragma unroll
  for (int off = 32; off; off >>= 1)
#pragma unroll
    for (int h = 0; h < NH_; ++h) p[h] += __shfl_xor(p[h], off);
  if (lane == 0) {
#pragma unroll
    for (int h = 0; h < NH_; ++h) {
      float x = p[h] + bias[h];
      delta[t * NH_ + h] = (x > 20.f) ? x : log1pf(__expf(x));
    }
  }
}

// ---- per-(chunk, head) delta sums ----
__global__ __launch_bounds__(512) void chunk_sums(const float* __restrict__ delta,
                                                  float* __restrict__ sumd) {
  int t = blockIdx.x * 512 + threadIdx.x;   // NCH_*16 = 1024
  int c = t >> 4, h = t & 15;
  float s = 0.f;
  const float* p = delta + (size_t)c * CT_ * NH_ + h;
#pragma unroll 8
  for (int j = 0; j < CT_; ++j) s += p[(size_t)j * NH_];
  sumd[t] = s;
}

// ======================= chunked selective scan ==========================
// r22-verified: 4ch x 16n; A pre-scaled by log2e; native v_exp; st bf16;
// u-tile staged in LDS.
__device__ __forceinline__ float rdlane(float v, int l) {
  return __builtin_bit_cast(float, __builtin_amdgcn_readlane(__builtin_bit_cast(int, v), l));
}

// ---- phase 1: local scan from zero (state only) ----
__global__ __launch_bounds__(256) void scan1(const short* __restrict__ hs,     // [L+1, I] bf16
                                             const float* __restrict__ Bm,     // [L, N]
                                             const float* __restrict__ delta,  // [L, NH]
                                             const float* __restrict__ A,      // [I, N]
                                             short* __restrict__ st) {         // [NCH][N][I] bf16
  __shared__ float sB[CT_ * 64];              // 8 KB
  __shared__ float su[CT_ * 256];             // 32 KB
  int tid = threadIdx.x;
  int lane = tid & 63, wv = tid >> 6;
  int c0b = blockIdx.x * 256;
  int c0w = c0b + wv * 64;
  int c = lane & 15, q = lane >> 4;
  int chunk = blockIdx.y;
  int t0 = chunk * CT_;
  int head = c0w >> 7;
  int nb = q * 16;
  int ch0 = c0w + c;
  int lu = wv * 64 + c;                       // local u index base

  { const float4* B4 = (const float4*)(Bm + (size_t)t0 * 64);
    float4* S4 = (float4*)sB;
    S4[tid] = B4[tid];
    S4[256 + tid] = B4[256 + tid]; }
  // stage u tile [32][256] bf16 -> f32 (4 coalesced short8 loads/thread)
  { int cc = tid & 31, tt0 = tid >> 5;
#pragma unroll
    for (int r = 0; r < 4; ++r) {
      int tt = r * 8 + tt0;
      s16x8 v = *(const s16x8*)(hs + (size_t)(t0 + tt) * I_ + c0b + cc * 8);
      float* dst = &su[tt * 256 + cc * 8];
      float4 lo = {bf2f((unsigned short)v[0]), bf2f((unsigned short)v[1]),
                   bf2f((unsigned short)v[2]), bf2f((unsigned short)v[3])};
      float4 hi = {bf2f((unsigned short)v[4]), bf2f((unsigned short)v[5]),
                   bf2f((unsigned short)v[6]), bf2f((unsigned short)v[7])};
      *(float4*)dst = lo;
      *(float4*)(dst + 4) = hi;
    } }
  float d_r = delta[(size_t)(t0 + (lane & 31)) * NH_ + head];

  float aL[4][16], s[4][16];
#pragma unroll
  for (int j = 0; j < 4; ++j) {
    const float* Ap = A + (size_t)(ch0 + 16 * j) * 64 + nb;
#pragma unroll
    for (int k4 = 0; k4 < 4; ++k4) {
      float4 av = *(const float4*)(Ap + k4 * 4);
      aL[j][k4*4+0] = av.x * LOG2E; aL[j][k4*4+1] = av.y * LOG2E;
      aL[j][k4*4+2] = av.z * LOG2E; aL[j][k4*4+3] = av.w * LOG2E;
    }
#pragma unroll
    for (int k = 0; k < 16; ++k) s[j][k] = 0.f;
  }
  __syncthreads();

#pragma unroll 1
  for (int t = 0; t < CT_; ++t) {
    float dlt = rdlane(d_r, t);
    const float* ut = &su[t * 256 + lu];
    float du0 = dlt * ut[0], du1 = dlt * ut[16], du2 = dlt * ut[32], du3 = dlt * ut[48];
    const float* bt = &sB[t * 64 + nb];
#pragma unroll
    for (int k4 = 0; k4 < 4; ++k4) {
      float4 b4 = *(const float4*)&bt[k4 * 4];
#pragma unroll
      for (int e = 0; e < 4; ++e) {
        int k = k4 * 4 + e; float bb = (&b4.x)[e];
        s[0][k] = s[0][k] * ex2(dlt * aL[0][k]) + du0 * bb;
        s[1][k] = s[1][k] * ex2(dlt * aL[1][k]) + du1 * bb;
        s[2][k] = s[2][k] * ex2(dlt * aL[2][k]) + du2 * bb;
        s[3][k] = s[3][k] * ex2(dlt * aL[3][k]) + du3 * bb;
      }
    }
  }
  size_t base = ((size_t)chunk << 17) + ch0;
#pragma unroll
  for (int j = 0; j < 4; ++j)
#pragma unroll
    for (int k = 0; k < 16; ++k)
      st[base + ((size_t)(nb + k) << 11) + 16 * j] = f2bf(s[j][k]);
}

// ---- phase 2: register-blocked sequential combine (loads all chunks) ----
__global__ __launch_bounds__(256) void scan2(const float* __restrict__ A,
                                             const float* __restrict__ sumd,  // [NCH*16]
                                             short* __restrict__ st) {        // [NCH][N][I] bf16
  int g = blockIdx.x * 256 + threadIdx.x;    // over N*I = 131072
  int i = g & (I_ - 1), n = g >> 11;
  int h = i >> 7;
  float aL = A[((size_t)i << 6) + n] * LOG2E;
  float loc[NCH_];
#pragma unroll
  for (int c = 0; c < NCH_; ++c)
    loc[c] = bf2f((unsigned short)st[((size_t)c << 17) + g]);
  float s = 0.f;
#pragma unroll
  for (int c = 0; c < NCH_; ++c) {
    float gfac = ex2(aL * sumd[c * 16 + h]);
    float nxt = s * gfac + loc[c];
    st[((size_t)c << 17) + g] = f2bf(s);      // incoming state for chunk c
    s = nxt;
  }
}

// ---- phase 3: recompute with incoming state + y + fused epilogue ----
__global__ __launch_bounds__(256) void scan3(const short* __restrict__ hs,     // [L+1, I] bf16
                                             const float* __restrict__ Bm,     // [L, N]
                                             const float* __restrict__ Cm,     // [L, N]
                                             const float* __restrict__ delta,  // [L, NH]
                                             const float* __restrict__ A,      // [I, N]
                                             const float* __restrict__ Dv,     // [I]
                                             const short* __restrict__ gate_b, // [L, I] bf16
                                             const short* __restrict__ st,     // [NCH][N][I] bf16
                                             short* __restrict__ ybf) {        // [L, I] bf16
  __shared__ float sB[CT_ * 64], sC[CT_ * 64];   // 16 KB
  __shared__ float su[CT_ * 256];                // 32 KB
  int tid = threadIdx.x;
  int lane = tid & 63, wv = tid >> 6;
  int c0b = blockIdx.x * 256;
  int c0w = c0b + wv * 64;
  int c = lane & 15, q = lane >> 4;
  int chunk = blockIdx.y;
  int t0 = chunk * CT_;
  int head = c0w >> 7;
  int nb = q * 16;
  int ch0 = c0w + c;
  int lu = wv * 64 + c;

  { const float4* B4 = (const float4*)(Bm + (size_t)t0 * 64);
    const float4* C4 = (const float4*)(Cm + (size_t)t0 * 64);
    float4* SB4 = (float4*)sB;
    float4* SC4 = (float4*)sC;
    SB4[tid] = B4[tid];       SB4[256 + tid] = B4[256 + tid];
    SC4[tid] = C4[tid];       SC4[256 + tid] = C4[256 + tid]; }
  // stage u tile [32][256] bf16 -> f32
  { int cc = tid & 31, tt0 = tid >> 5;
#pragma unroll
    for (int r = 0; r < 4; ++r) {
      int tt = r * 8 + tt0;
      s16x8 v = *(const s16x8*)(hs + (size_t)(t0 + tt) * I_ + c0b + cc * 8);
      float* dst = &su[tt * 256 + cc * 8];
      float4 lo = {bf2f((unsigned short)v[0]), bf2f((unsigned short)v[1]),
                   bf2f((unsigned short)v[2]), bf2f((unsigned short)v[3])};
      float4 hi = {bf2f((unsigned short)v[4]), bf2f((unsigned short)v[5]),
                   bf2f((unsigned short)v[6]), bf2f((unsigned short)v[7])};
      *(float4*)dst = lo;
      *(float4*)(dst + 4) = hi;
    } }
  float d_r = delta[(size_t)(t0 + (lane & 31)) * NH_ + head];
  float D_own = Dv[c0w + lane];

  float aL[4][16], s[4][16];
#pragma unroll
  for (int j = 0; j < 4; ++j) {
    const float* Ap = A + (size_t)(ch0 + 16 * j) * 64 + nb;
#pragma unroll
    for (int k4 = 0; k4 < 4; ++k4) {
      float4 av = *(const float4*)(Ap + k4 * 4);
      aL[j][k4*4+0] = av.x * LOG2E; aL[j][k4*4+1] = av.y * LOG2E;
      aL[j][k4*4+2] = av.z * LOG2E; aL[j][k4*4+3] = av.w * LOG2E;
    }
  }
  { size_t base = ((size_t)chunk << 17) + ch0;
#pragma unroll
    for (int j = 0; j < 4; ++j)
#pragma unroll
      for (int k = 0; k < 16; ++k)
        s[j][k] = bf2f((unsigned short)st[base + ((size_t)(nb + k) << 11) + 16 * j]);
  }
  __syncthreads();

  const short* gp = gate_b + (size_t)t0 * I_ + c0w + lane;
  short* yp = ybf + (size_t)t0 * I_ + c0w + lane;
  bool b4f = lane & 16, b5f = lane & 32;
#pragma unroll 1
  for (int t = 0; t < CT_; ++t) {
    float gv = bf2f((unsigned short)gp[(size_t)t * I_]);
    float dlt = rdlane(d_r, t);
    const float* ut = &su[t * 256 + lu];
    float du0 = dlt * ut[0], du1 = dlt * ut[16], du2 = dlt * ut[32], du3 = dlt * ut[48];
    float u_own = su[t * 256 + wv * 64 + lane];
    const float* bt = &sB[t * 64 + nb];
    const float* ct = &sC[t * 64 + nb];
    float p0 = 0.f, p1 = 0.f, p2 = 0.f, p3 = 0.f;
#pragma unroll
    for (int k4 = 0; k4 < 4; ++k4) {
      float4 b4 = *(const float4*)&bt[k4 * 4];
      float4 c4 = *(const float4*)&ct[k4 * 4];
#pragma unroll
      for (int e = 0; e < 4; ++e) {
        int k = k4 * 4 + e;
        float bb = (&b4.x)[e], cc = (&c4.x)[e];
        s[0][k] = s[0][k] * ex2(dlt * aL[0][k]) + du0 * bb;  p0 += s[0][k] * cc;
        s[1][k] = s[1][k] * ex2(dlt * aL[1][k]) + du1 * bb;  p1 += s[1][k] * cc;
        s[2][k] = s[2][k] * ex2(dlt * aL[2][k]) + du2 * bb;  p2 += s[2][k] * cc;
        s[3][k] = s[3][k] * ex2(dlt * aL[3][k]) + du3 * bb;  p3 += s[3][k] * cc;
      }
    }
    // reduce over n-quarters; lane (q,c) ends with y for channel c0w+lane
    float sa = b5f ? p0 : p2;
    float sb = b5f ? p1 : p3;
    float qa = (b5f ? p2 : p0) + __shfl_xor(sa, 32);
    float qb = (b5f ? p3 : p1) + __shfl_xor(sb, 32);
    float sc = b4f ? qa : qb;
    float y  = (b4f ? qb : qa) + __shfl_xor(sc, 16);
    y += D_own * u_own;
    yp[(size_t)t * I_] = f2bf(y * gv);
  }
}

extern "C" void kernel_launch(void* const* d_in, const int* in_sizes, int n_in,
                              void* d_out, int out_size, void* d_ws, size_t ws_size,
                              hipStream_t stream) {
  const float* hidden  = (const float*)d_in[0];
  const float* inproj  = (const float*)d_in[1];
  const float* convw   = (const float*)d_in[2];
  const float* bcdtw   = (const float*)d_in[3];
  const float* dtnw    = (const float*)d_in[4];
  const float* Bnw     = (const float*)d_in[5];
  const float* Cnw     = (const float*)d_in[6];
  const float* dtpw    = (const float*)d_in[7];
  const float* dtbias  = (const float*)d_in[8];
  const float* Amat    = (const float*)d_in[9];
  const float* Dvec    = (const float*)d_in[10];
  const float* outproj = (const float*)d_in[11];
  float* out = (float*)d_out;

  char* ws = (char*)d_ws;
  short* inproj_p  = (short*)ws; ws += (size_t)H_ * 2 * I_ * 2;   // 16 MB
  short* bcdt_p    = (short*)ws; ws += (size_t)I_ * 256 * 2;
  short* outproj_p = (short*)ws; ws += (size_t)I_ * H_ * 2;
  short* hid_b     = (short*)ws; ws += (size_t)L_ * H_ * 2;
  float* proj      = (float*)ws; ws += (size_t)L_ * 2 * I_ * 4;   // 32 MB
  short* hs_b      = (short*)ws; ws += (size_t)(L_ + 1) * I_ * 2; // +1 pad row
  short* gate_b    = (short*)ws; ws += (size_t)L_ * I_ * 2;       // 8 MB
  float* ssmp      = (float*)ws; ws += (size_t)L_ * 256 * 4;
  float* Bmat      = (float*)ws; ws += (size_t)L_ * NS_ * 4;
  float* Cmat      = (float*)ws; ws += (size_t)L_ * NS_ * 4;
  float* delta     = (float*)ws; ws += (size_t)L_ * NH_ * 4;
  short* y_b       = (short*)ws; ws += (size_t)L_ * I_ * 2;
  float* sumd      = (float*)ws; ws += NCH_ * 16 * 4;
  // chunk-state buffer [NCH][N][I] bf16 = 16 MB: aliases proj, dead after
  // conv_silu (gate extracted to gate_b).  Stream-ordered each launch.
  short* sstate    = (short*)proj;

  pack_w8<<<(H_ * 2 * I_ / 8 + 255) / 256, 256, 0, stream>>>(inproj, inproj_p, H_ * 2 * I_ / 8, 12);
  pack_w8<<<(I_ * 256 / 8 + 255) / 256, 256, 0, stream>>>(bcdtw, bcdt_p, I_ * 256 / 8, 8);
  pack_w8<<<(I_ * H_ / 8 + 255) / 256, 256, 0, stream>>>(outproj, outproj_p, I_ * H_ / 8, 11);
  cast_bf<<<(L_ * H_ + 255) / 256, 256, 0, stream>>>(hidden, hid_b, L_ * H_);

  gemm_st<128><<<dim3(L_ / 128, (2 * I_) / 128), 256, 0, stream>>>(hid_b, inproj_p, proj, L_, 2 * I_, H_);
  conv_silu<<<(L_ * I_) / 256, 256, 0, stream>>>(proj, convw, hs_b, gate_b);
  gemm_st<64><<<dim3(L_ / 64, 256 / 128), 256, 0, stream>>>(hs_b, bcdt_p, ssmp, L_, 256, I_);
  norm_dt<<<L_ / 4, 256, 0, stream>>>(ssmp, Bnw, Cnw, dtnw, dtpw, dtbias, Bmat, Cmat, delta);

  chunk_sums<<<(NCH_ * 16) / 512, 512, 0, stream>>>(delta, sumd);
  scan1<<<dim3(I_ / 256, NCH_), 256, 0, stream>>>(hs_b, Bmat, delta, Amat, sstate);
  scan2<<<(I_ * 64) / 256, 256, 0, stream>>>(Amat, sumd, sstate);
  scan3<<<dim3(I_ / 256, NCH_), 256, 0, stream>>>(hs_b, Bmat, Cmat, delta, Amat, Dvec, gate_b, sstate, y_b);

  gemm_st<64><<<dim3(L_ / 64, H_ / 128), 256, 0, stream>>>(y_b, outproj_p, out, L_, H_, I_);
}

// Round 24
// 264.342 us; speedup vs baseline: 1.0466x; 1.0012x over previous
//
#include <hip/hip_runtime.h>
#include <hip/hip_bf16.h>

// dims (fixed per reference)
#define L_   2048
#define H_   2048
#define I_   2048
#define NH_  16
#define HPH_ 128
#define NS_  64
#define R_   128
#define NCH_ 64     // chunks
#define CT_  32     // steps per chunk
#define LOG2E 1.4426950408889634f

typedef __attribute__((ext_vector_type(8))) short s16x8;
typedef __attribute__((ext_vector_type(4))) float f32x4;

__device__ __forceinline__ short f2bf(float x) {
  unsigned u = __builtin_bit_cast(unsigned, x);
  u += 0x7fff + ((u >> 16) & 1);   // round-to-nearest-even
  return (short)(u >> 16);
}
__device__ __forceinline__ float bf2f(unsigned short v) {
  return __builtin_bit_cast(float, (unsigned)v << 16);
}

// native v_exp_f32 (2^x), no libm guard code
__device__ __forceinline__ float ex2(float x) {
  return __builtin_amdgcn_exp2f(x);
}

// async global->LDS, 16B per lane; LDS dest = wave-uniform base + lane*16
__device__ __forceinline__ void gll16(const void* g, void* l) {
  __builtin_amdgcn_global_load_lds(
      (__attribute__((address_space(1))) void*)(void*)g,
      (__attribute__((address_space(3))) void*)l, 16, 0, 0);
}

// ---- pack weight W[K][N] (f32 row-major) -> Wp[(k>>3)][n][k%8] bf16 ----
// thread = (k-group, n): 8 coalesced strided reads + ONE contiguous short8
// write (16B/lane -> 1KB/wave, no write amplification).
__global__ __launch_bounds__(256) void pack_w8(const float* __restrict__ W,
                                               short* __restrict__ Wp,
                                               int KN8, int logN) {
  int idx = blockIdx.x * 256 + threadIdx.x;   // over K*N/8
  if (idx >= KN8) return;
  int kg = idx >> logN;
  int n = idx & ((1 << logN) - 1);
  const float* src = W + ((size_t)(kg * 8) << logN) + n;
  s16x8 v;
#pragma unroll
  for (int j = 0; j < 8; ++j) v[j] = f2bf(src[(size_t)j << logN]);
  *(s16x8*)(Wp + ((size_t)kg << (logN + 3)) + ((size_t)n << 3)) = v;
}

__global__ __launch_bounds__(256) void cast_bf(const float* __restrict__ X,
                                               short* __restrict__ Xb, int nElem) {
  int idx = blockIdx.x * 256 + threadIdx.x;
  if (idx < nElem) Xb[idx] = f2bf(X[idx]);
}

// ---- staged bf16 MFMA GEMM (m97 structure) + bijective XCD swizzle ----
// BF16OUT: write C as bf16 (for proj, whose only consumer re-quantizes anyway)
template<int BM, bool BF16OUT>
__global__ __launch_bounds__(256) void gemm_st(const short* __restrict__ A,
                                               const short* __restrict__ Bp,
                                               void* __restrict__ Cv,
                                               int M, int N, int K) {
  constexpr int MI = BM / 32;                 // m-fragments per wave
  __shared__ short sA[BM * 64];               // [BM][64] bf16, swizzled
  __shared__ short sB[8 * 128 * 8];           // [kg][n][8] bf16, linear
  int tid = threadIdx.x;
  int lane = tid & 63, wid = tid >> 6;
  int wr = wid >> 1, wc = wid & 1;
  int l15 = lane & 15, l16 = lane >> 4;

  // XCD-aware bijective swizzle (nwg % 8 == 0 for all our grids)
  int nwg = gridDim.x * gridDim.y;
  int lin = blockIdx.x + gridDim.x * blockIdx.y;
  int cpx = nwg >> 3;
  int swz = (lin & 7) * cpx + (lin >> 3);
  int bm = (swz % gridDim.x) * BM, bn = (swz / gridDim.x) * 128;

  f32x4 acc[MI][4] = {};

  int arow = lane >> 3;                       // row within 8-row group
  int acolb = ((lane & 7) ^ arow) * 16;       // inverse-swizzled source byte
  const char* Ag = (const char*)(A + (size_t)bm * K) + acolb;
  const char* Bg = (const char*)(Bp + (size_t)bn * 8);

  for (int k0 = 0; k0 < K; k0 += 64) {
    __syncthreads();
#pragma unroll
    for (int q = 0; q < BM / 32; ++q) {       // stage A: 1KB per inst
      int rbase = (q * 4 + wid) * 8;
      gll16(Ag + ((size_t)(rbase + arow) * K + k0) * 2,
            (char*)sA + rbase * 128);
    }
#pragma unroll
    for (int q = 0; q < 4; ++q) {             // stage B: 1KB per inst
      int c = q * 4 + wid;
      int kg = c >> 1, nh = (c & 1) * 64;
      gll16(Bg + ((size_t)(k0 / 8 + kg) * N * 8 + (size_t)(nh + lane) * 8) * 2,
            (char*)sB + kg * 2048 + nh * 16);
    }
    __syncthreads();

#pragma unroll
    for (int kk = 0; kk < 64; kk += 32) {
      s16x8 a[MI], b[4];
#pragma unroll
      for (int mi = 0; mi < MI; ++mi) {
        int row = wr * (BM / 2) + mi * 16 + l15;
        int kb = ((kk + l16 * 8) * 2) ^ ((row & 7) << 4);   // swizzled read
        a[mi] = *(const s16x8*)((const char*)sA + row * 128 + kb);
      }
#pragma unroll
      for (int ni = 0; ni < 4; ++ni) {
        int n = wc * 64 + ni * 16 + l15;
        int kg = (kk >> 3) + l16;
        b[ni] = *(const s16x8*)((const char*)sB + (kg * 128 + n) * 16);
      }
#pragma unroll
      for (int mi = 0; mi < MI; ++mi)
#pragma unroll
        for (int ni = 0; ni < 4; ++ni)
          acc[mi][ni] = __builtin_amdgcn_mfma_f32_16x16x32_bf16(a[mi], b[ni], acc[mi][ni], 0, 0, 0);
    }
  }
#pragma unroll
  for (int mi = 0; mi < MI; ++mi) {
    int row0 = bm + wr * (BM / 2) + mi * 16 + l16 * 4;
#pragma unroll
    for (int ni = 0; ni < 4; ++ni) {
      int col = bn + wc * 64 + ni * 16 + l15;
#pragma unroll
      for (int r = 0; r < 4; ++r) {
        if constexpr (BF16OUT)
          ((short*)Cv)[(size_t)(row0 + r) * N + col] = f2bf(acc[mi][ni][r]);
        else
          ((float*)Cv)[(size_t)(row0 + r) * N + col] = acc[mi][ni][r];
      }
    }
  }
}

// ---- causal depthwise conv (K=4) + SiLU -> bf16; silu(gate) -> bf16 ----
// proj now bf16
__global__ __launch_bounds__(256) void conv_silu(const short* __restrict__ proj,
                                                 const float* __restrict__ convw,
                                                 short* __restrict__ hsb,
                                                 short* __restrict__ gate_b) {
  int idx = blockIdx.x * 256 + threadIdx.x;   // over L_*I_
  int t = idx >> 11, i = idx & (I_ - 1);
  int col = ((i >> 7) << 8) + 128 + (i & 127);  // head*256 + 128 + (i%128)
  float4 cw = *(const float4*)(convw + i * 4);
  const short* p = proj + (size_t)t * (2 * I_) + col;
  float acc = cw.w * bf2f((unsigned short)p[0]);
  if (t >= 1) acc += cw.z * bf2f((unsigned short)p[-(2 * I_)]);
  if (t >= 2) acc += cw.y * bf2f((unsigned short)p[-(2 * I_) * 2]);
  if (t >= 3) acc += cw.x * bf2f((unsigned short)p[-(2 * I_) * 3]);
  float h = acc / (1.f + __expf(-acc));   // silu
  hsb[idx] = f2bf(h);
  float g = bf2f((unsigned short)p[-128]);  // gate element for channel i
  gate_b[idx] = f2bf(g / (1.f + __expf(-g)));   // silu(gate)
}

// ---- RMSNorms (B, C, ts) + dt = ts@dt_proj + softplus(dt + bias) ----
__global__ __launch_bounds__(256) void norm_dt(const float* __restrict__ sp,
                                               const float* __restrict__ Bw,
                                               const float* __restrict__ Cw,
                                               const float* __restrict__ dtw,
                                               const float* __restrict__ Wdt,
                                               const float* __restrict__ bias,
                                               float* __restrict__ Bo,
                                               float* __restrict__ Co,
                                               float* __restrict__ delta) {
  int lane = threadIdx.x & 63, w = threadIdx.x >> 6;
  int t = blockIdx.x * 4 + w;
  const float* row = sp + (size_t)t * 256;
  float v0 = row[lane], v1 = row[64 + lane], v2 = row[128 + lane], v3 = row[192 + lane];
  float sB = v0 * v0, sC = v1 * v1, sT = v2 * v2 + v3 * v3;
#pragma unroll
  for (int off = 32; off; off >>= 1) {
    sB += __shfl_xor(sB, off);
    sC += __shfl_xor(sC, off);
    sT += __shfl_xor(sT, off);
  }
  float rB = rsqrtf(sB * (1.f / 64) + 1e-6f);
  float rC = rsqrtf(sC * (1.f / 64) + 1e-6f);
  float rT = rsqrtf(sT * (1.f / 128) + 1e-6f);
  Bo[t * 64 + lane] = v0 * rB * Bw[lane];
  Co[t * 64 + lane] = v1 * rC * Cw[lane];
  float t2 = v2 * rT * dtw[lane], t3 = v3 * rT * dtw[64 + lane];
  float p[NH_];
  const float* w0 = Wdt + lane * NH_;
  const float* w1 = Wdt + (64 + lane) * NH_;
#pragma unroll
  for (int h = 0; h < NH_; ++h) p[h] = t2 * w0[h] + t3 * w1[h];
#pragma unroll
  for (int off = 32; off; off >>= 1)
#pragma unroll
    for (int h = 0; h < NH_; ++h) p[h] += __shfl_xor(p[h], off);
  if (lane == 0) {
#pragma unroll
    for (int h = 0; h < NH_; ++h) {
      float x = p[h] + bias[h];
      delta[t * NH_ + h] = (x > 20.f) ? x : log1pf(__expf(x));
    }
  }
}

// ---- per-(chunk, head) delta sums ----
__global__ __launch_bounds__(512) void chunk_sums(const float* __restrict__ delta,
                                                  float* __restrict__ sumd) {
  int t = blockIdx.x * 512 + threadIdx.x;   // NCH_*16 = 1024
  int c = t >> 4, h = t & 15;
  float s = 0.f;
  const float* p = delta + (size_t)c * CT_ * NH_ + h;
#pragma unroll 8
  for (int j = 0; j < CT_; ++j) s += p[(size_t)j * NH_];
  sumd[t] = s;
}

// ======================= chunked selective scan ==========================
// r22-verified: 4ch x 16n; A pre-scaled by log2e; native v_exp; st bf16;
// u-tile staged in LDS.
__device__ __forceinline__ float rdlane(float v, int l) {
  return __builtin_bit_cast(float, __builtin_amdgcn_readlane(__builtin_bit_cast(int, v), l));
}

// ---- phase 1: local scan from zero (state only) ----
__global__ __launch_bounds__(256) void scan1(const short* __restrict__ hs,     // [L+1, I] bf16
                                             const float* __restrict__ Bm,     // [L, N]
                                             const float* __restrict__ delta,  // [L, NH]
                                             const float* __restrict__ A,      // [I, N]
                                             short* __restrict__ st) {         // [NCH][N][I] bf16
  __shared__ float sB[CT_ * 64];              // 8 KB
  __shared__ float su[CT_ * 256];             // 32 KB
  int tid = threadIdx.x;
  int lane = tid & 63, wv = tid >> 6;
  int c0b = blockIdx.x * 256;
  int c0w = c0b + wv * 64;
  int c = lane & 15, q = lane >> 4;
  int chunk = blockIdx.y;
  int t0 = chunk * CT_;
  int head = c0w >> 7;
  int nb = q * 16;
  int ch0 = c0w + c;
  int lu = wv * 64 + c;                       // local u index base

  { const float4* B4 = (const float4*)(Bm + (size_t)t0 * 64);
    float4* S4 = (float4*)sB;
    S4[tid] = B4[tid];
    S4[256 + tid] = B4[256 + tid]; }
  // stage u tile [32][256] bf16 -> f32 (4 coalesced short8 loads/thread)
  { int cc = tid & 31, tt0 = tid >> 5;
#pragma unroll
    for (int r = 0; r < 4; ++r) {
      int tt = r * 8 + tt0;
      s16x8 v = *(const s16x8*)(hs + (size_t)(t0 + tt) * I_ + c0b + cc * 8);
      float* dst = &su[tt * 256 + cc * 8];
      float4 lo = {bf2f((unsigned short)v[0]), bf2f((unsigned short)v[1]),
                   bf2f((unsigned short)v[2]), bf2f((unsigned short)v[3])};
      float4 hi = {bf2f((unsigned short)v[4]), bf2f((unsigned short)v[5]),
                   bf2f((unsigned short)v[6]), bf2f((unsigned short)v[7])};
      *(float4*)dst = lo;
      *(float4*)(dst + 4) = hi;
    } }
  float d_r = delta[(size_t)(t0 + (lane & 31)) * NH_ + head];

  float aL[4][16], s[4][16];
#pragma unroll
  for (int j = 0; j < 4; ++j) {
    const float* Ap = A + (size_t)(ch0 + 16 * j) * 64 + nb;
#pragma unroll
    for (int k4 = 0; k4 < 4; ++k4) {
      float4 av = *(const float4*)(Ap + k4 * 4);
      aL[j][k4*4+0] = av.x * LOG2E; aL[j][k4*4+1] = av.y * LOG2E;
      aL[j][k4*4+2] = av.z * LOG2E; aL[j][k4*4+3] = av.w * LOG2E;
    }
#pragma unroll
    for (int k = 0; k < 16; ++k) s[j][k] = 0.f;
  }
  __syncthreads();

#pragma unroll 1
  for (int t = 0; t < CT_; ++t) {
    float dlt = rdlane(d_r, t);
    const float* ut = &su[t * 256 + lu];
    float du0 = dlt * ut[0], du1 = dlt * ut[16], du2 = dlt * ut[32], du3 = dlt * ut[48];
    const float* bt = &sB[t * 64 + nb];
#pragma unroll
    for (int k4 = 0; k4 < 4; ++k4) {
      float4 b4 = *(const float4*)&bt[k4 * 4];
#pragma unroll
      for (int e = 0; e < 4; ++e) {
        int k = k4 * 4 + e; float bb = (&b4.x)[e];
        s[0][k] = s[0][k] * ex2(dlt * aL[0][k]) + du0 * bb;
        s[1][k] = s[1][k] * ex2(dlt * aL[1][k]) + du1 * bb;
        s[2][k] = s[2][k] * ex2(dlt * aL[2][k]) + du2 * bb;
        s[3][k] = s[3][k] * ex2(dlt * aL[3][k]) + du3 * bb;
      }
    }
  }
  size_t base = ((size_t)chunk << 17) + ch0;
#pragma unroll
  for (int j = 0; j < 4; ++j)
#pragma unroll
    for (int k = 0; k < 16; ++k)
      st[base + ((size_t)(nb + k) << 11) + 16 * j] = f2bf(s[j][k]);
}

// ---- phase 2: register-blocked sequential combine (loads all chunks) ----
__global__ __launch_bounds__(256) void scan2(const float* __restrict__ A,
                                             const float* __restrict__ sumd,  // [NCH*16]
                                             short* __restrict__ st) {        // [NCH][N][I] bf16
  int g = blockIdx.x * 256 + threadIdx.x;    // over N*I = 131072
  int i = g & (I_ - 1), n = g >> 11;
  int h = i >> 7;
  float aL = A[((size_t)i << 6) + n] * LOG2E;
  float loc[NCH_];
#pragma unroll
  for (int c = 0; c < NCH_; ++c)
    loc[c] = bf2f((unsigned short)st[((size_t)c << 17) + g]);
  float s = 0.f;
#pragma unroll
  for (int c = 0; c < NCH_; ++c) {
    float gfac = ex2(aL * sumd[c * 16 + h]);
    float nxt = s * gfac + loc[c];
    st[((size_t)c << 17) + g] = f2bf(s);      // incoming state for chunk c
    s = nxt;
  }
}

// ---- phase 3: recompute with incoming state + y + fused epilogue ----
__global__ __launch_bounds__(256) void scan3(const short* __restrict__ hs,     // [L+1, I] bf16
                                             const float* __restrict__ Bm,     // [L, N]
                                             const float* __restrict__ Cm,     // [L, N]
                                             const float* __restrict__ delta,  // [L, NH]
                                             const float* __restrict__ A,      // [I, N]
                                             const float* __restrict__ Dv,     // [I]
                                             const short* __restrict__ gate_b, // [L, I] bf16
                                             const short* __restrict__ st,     // [NCH][N][I] bf16
                                             short* __restrict__ ybf) {        // [L, I] bf16
  __shared__ float sB[CT_ * 64], sC[CT_ * 64];   // 16 KB
  __shared__ float su[CT_ * 256];                // 32 KB
  int tid = threadIdx.x;
  int lane = tid & 63, wv = tid >> 6;
  int c0b = blockIdx.x * 256;
  int c0w = c0b + wv * 64;
  int c = lane & 15, q = lane >> 4;
  int chunk = blockIdx.y;
  int t0 = chunk * CT_;
  int head = c0w >> 7;
  int nb = q * 16;
  int ch0 = c0w + c;
  int lu = wv * 64 + c;

  { const float4* B4 = (const float4*)(Bm + (size_t)t0 * 64);
    const float4* C4 = (const float4*)(Cm + (size_t)t0 * 64);
    float4* SB4 = (float4*)sB;
    float4* SC4 = (float4*)sC;
    SB4[tid] = B4[tid];       SB4[256 + tid] = B4[256 + tid];
    SC4[tid] = C4[tid];       SC4[256 + tid] = C4[256 + tid]; }
  // stage u tile [32][256] bf16 -> f32
  { int cc = tid & 31, tt0 = tid >> 5;
#pragma unroll
    for (int r = 0; r < 4; ++r) {
      int tt = r * 8 + tt0;
      s16x8 v = *(const s16x8*)(hs + (size_t)(t0 + tt) * I_ + c0b + cc * 8);
      float* dst = &su[tt * 256 + cc * 8];
      float4 lo = {bf2f((unsigned short)v[0]), bf2f((unsigned short)v[1]),
                   bf2f((unsigned short)v[2]), bf2f((unsigned short)v[3])};
      float4 hi = {bf2f((unsigned short)v[4]), bf2f((unsigned short)v[5]),
                   bf2f((unsigned short)v[6]), bf2f((unsigned short)v[7])};
      *(float4*)dst = lo;
      *(float4*)(dst + 4) = hi;
    } }
  float d_r = delta[(size_t)(t0 + (lane & 31)) * NH_ + head];
  float D_own = Dv[c0w + lane];

  float aL[4][16], s[4][16];
#pragma unroll
  for (int j = 0; j < 4; ++j) {
    const float* Ap = A + (size_t)(ch0 + 16 * j) * 64 + nb;
#pragma unroll
    for (int k4 = 0; k4 < 4; ++k4) {
      float4 av = *(const float4*)(Ap + k4 * 4);
      aL[j][k4*4+0] = av.x * LOG2E; aL[j][k4*4+1] = av.y * LOG2E;
      aL[j][k4*4+2] = av.z * LOG2E; aL[j][k4*4+3] = av.w * LOG2E;
    }
  }
  { size_t base = ((size_t)chunk << 17) + ch0;
#pragma unroll
    for (int j = 0; j < 4; ++j)
#pragma unroll
      for (int k = 0; k < 16; ++k)
        s[j][k] = bf2f((unsigned short)st[base + ((size_t)(nb + k) << 11) + 16 * j]);
  }
  __syncthreads();

  const short* gp = gate_b + (size_t)t0 * I_ + c0w + lane;
  short* yp = ybf + (size_t)t0 * I_ + c0w + lane;
  bool b4f = lane & 16, b5f = lane & 32;
#pragma unroll 1
  for (int t = 0; t < CT_; ++t) {
    float gv = bf2f((unsigned short)gp[(size_t)t * I_]);
    float dlt = rdlane(d_r, t);
    const float* ut = &su[t * 256 + lu];
    float du0 = dlt * ut[0], du1 = dlt * ut[16], du2 = dlt * ut[32], du3 = dlt * ut[48];
    float u_own = su[t * 256 + wv * 64 + lane];
    const float* bt = &sB[t * 64 + nb];
    const float* ct = &sC[t * 64 + nb];
    float p0 = 0.f, p1 = 0.f, p2 = 0.f, p3 = 0.f;
#pragma unroll
    for (int k4 = 0; k4 < 4; ++k4) {
      float4 b4 = *(const float4*)&bt[k4 * 4];
      float4 c4 = *(const float4*)&ct[k4 * 4];
#pragma unroll
      for (int e = 0; e < 4; ++e) {
        int k = k4 * 4 + e;
        float bb = (&b4.x)[e], cc = (&c4.x)[e];
        s[0][k] = s[0][k] * ex2(dlt * aL[0][k]) + du0 * bb;  p0 += s[0][k] * cc;
        s[1][k] = s[1][k] * ex2(dlt * aL[1][k]) + du1 * bb;  p1 += s[1][k] * cc;
        s[2][k] = s[2][k] * ex2(dlt * aL[2][k]) + du2 * bb;  p2 += s[2][k] * cc;
        s[3][k] = s[3][k] * ex2(dlt * aL[3][k]) + du3 * bb;  p3 += s[3][k] * cc;
      }
    }
    // reduce over n-quarters; lane (q,c) ends with y for channel c0w+lane
    float sa = b5f ? p0 : p2;
    float sb = b5f ? p1 : p3;
    float qa = (b5f ? p2 : p0) + __shfl_xor(sa, 32);
    float qb = (b5f ? p3 : p1) + __shfl_xor(sb, 32);
    float sc = b4f ? qa : qb;
    float y  = (b4f ? qb : qa) + __shfl_xor(sc, 16);
    y += D_own * u_own;
    yp[(size_t)t * I_] = f2bf(y * gv);
  }
}

extern "C" void kernel_launch(void* const* d_in, const int* in_sizes, int n_in,
                              void* d_out, int out_size, void* d_ws, size_t ws_size,
                              hipStream_t stream) {
  const float* hidden  = (const float*)d_in[0];
  const float* inproj  = (const float*)d_in[1];
  const float* convw   = (const float*)d_in[2];
  const float* bcdtw   = (const float*)d_in[3];
  const float* dtnw    = (const float*)d_in[4];
  const float* Bnw     = (const float*)d_in[5];
  const float* Cnw     = (const float*)d_in[6];
  const float* dtpw    = (const float*)d_in[7];
  const float* dtbias  = (const float*)d_in[8];
  const float* Amat    = (const float*)d_in[9];
  const float* Dvec    = (const float*)d_in[10];
  const float* outproj = (const float*)d_in[11];
  float* out = (float*)d_out;

  char* ws = (char*)d_ws;
  short* inproj_p  = (short*)ws; ws += (size_t)H_ * 2 * I_ * 2;   // 16 MB
  short* bcdt_p    = (short*)ws; ws += (size_t)I_ * 256 * 2;
  short* outproj_p = (short*)ws; ws += (size_t)I_ * H_ * 2;
  short* hid_b     = (short*)ws; ws += (size_t)L_ * H_ * 2;
  short* proj_b    = (short*)ws; ws += (size_t)L_ * 2 * I_ * 2;   // 16 MB bf16
  short* hs_b      = (short*)ws; ws += (size_t)(L_ + 1) * I_ * 2; // +1 pad row
  short* gate_b    = (short*)ws; ws += (size_t)L_ * I_ * 2;       // 8 MB
  float* ssmp      = (float*)ws; ws += (size_t)L_ * 256 * 4;
  float* Bmat      = (float*)ws; ws += (size_t)L_ * NS_ * 4;
  float* Cmat      = (float*)ws; ws += (size_t)L_ * NS_ * 4;
  float* delta     = (float*)ws; ws += (size_t)L_ * NH_ * 4;
  short* y_b       = (short*)ws; ws += (size_t)L_ * I_ * 2;
  float* sumd      = (float*)ws; ws += NCH_ * 16 * 4;
  // chunk-state buffer [NCH][N][I] bf16 = 16 MB: aliases proj_b (same size),
  // dead after conv_silu (gate extracted to gate_b).  Stream-ordered.
  short* sstate    = proj_b;

  pack_w8<<<(H_ * 2 * I_ / 8 + 255) / 256, 256, 0, stream>>>(inproj, inproj_p, H_ * 2 * I_ / 8, 12);
  pack_w8<<<(I_ * 256 / 8 + 255) / 256, 256, 0, stream>>>(bcdtw, bcdt_p, I_ * 256 / 8, 8);
  pack_w8<<<(I_ * H_ / 8 + 255) / 256, 256, 0, stream>>>(outproj, outproj_p, I_ * H_ / 8, 11);
  cast_bf<<<(L_ * H_ + 255) / 256, 256, 0, stream>>>(hidden, hid_b, L_ * H_);

  gemm_st<128, true><<<dim3(L_ / 128, (2 * I_) / 128), 256, 0, stream>>>(hid_b, inproj_p, proj_b, L_, 2 * I_, H_);
  conv_silu<<<(L_ * I_) / 256, 256, 0, stream>>>(proj_b, convw, hs_b, gate_b);
  gemm_st<64, false><<<dim3(L_ / 64, 256 / 128), 256, 0, stream>>>(hs_b, bcdt_p, ssmp, L_, 256, I_);
  norm_dt<<<L_ / 4, 256, 0, stream>>>(ssmp, Bnw, Cnw, dtnw, dtpw, dtbias, Bmat, Cmat, delta);

  chunk_sums<<<(NCH_ * 16) / 512, 512, 0, stream>>>(delta, sumd);
  scan1<<<dim3(I_ / 256, NCH_), 256, 0, stream>>>(hs_b, Bmat, delta, Amat, sstate);
  scan2<<<(I_ * 64) / 256, 256, 0, stream>>>(Amat, sumd, sstate);
  scan3<<<dim3(I_ / 256, NCH_), 256, 0, stream>>>(hs_b, Bmat, Cmat, delta, Amat, Dvec, gate_b, sstate, y_b);

  gemm_st<64, false><<<dim3(L_ / 64, H_ / 128), 256, 0, stream>>>(y_b, outproj_p, out, L_, H_, I_);
}

// Round 25
// 263.782 us; speedup vs baseline: 1.0488x; 1.0021x over previous
//
#include <hip/hip_runtime.h>
#include <hip/hip_bf16.h>

// dims (fixed per reference)
#define L_   2048
#define H_   2048
#define I_   2048
#define NH_  16
#define HPH_ 128
#define NS_  64
#define R_   128
#define NCH_ 64     // chunks
#define CT_  32     // steps per chunk
#define LOG2E 1.4426950408889634f

typedef __attribute__((ext_vector_type(8))) short s16x8;
typedef __attribute__((ext_vector_type(4))) float f32x4;

__device__ __forceinline__ short f2bf(float x) {
  unsigned u = __builtin_bit_cast(unsigned, x);
  u += 0x7fff + ((u >> 16) & 1);   // round-to-nearest-even
  return (short)(u >> 16);
}
__device__ __forceinline__ float bf2f(unsigned short v) {
  return __builtin_bit_cast(float, (unsigned)v << 16);
}

// native v_exp_f32 (2^x), no libm guard code
__device__ __forceinline__ float ex2(float x) {
  return __builtin_amdgcn_exp2f(x);
}

// async global->LDS, 16B per lane; LDS dest = wave-uniform base + lane*16
__device__ __forceinline__ void gll16(const void* g, void* l) {
  __builtin_amdgcn_global_load_lds(
      (__attribute__((address_space(1))) void*)(void*)g,
      (__attribute__((address_space(3))) void*)l, 16, 0, 0);
}

// ---- pack weight W[K][N] (f32 row-major) -> Wp[(k>>3)][n][k%8] bf16 ----
// thread = (k-group, n): 8 coalesced strided reads + ONE contiguous short8
// write (16B/lane -> 1KB/wave, no write amplification).
__global__ __launch_bounds__(256) void pack_w8(const float* __restrict__ W,
                                               short* __restrict__ Wp,
                                               int KN8, int logN) {
  int idx = blockIdx.x * 256 + threadIdx.x;   // over K*N/8
  if (idx >= KN8) return;
  int kg = idx >> logN;
  int n = idx & ((1 << logN) - 1);
  const float* src = W + ((size_t)(kg * 8) << logN) + n;
  s16x8 v;
#pragma unroll
  for (int j = 0; j < 8; ++j) v[j] = f2bf(src[(size_t)j << logN]);
  *(s16x8*)(Wp + ((size_t)kg << (logN + 3)) + ((size_t)n << 3)) = v;
}

__global__ __launch_bounds__(256) void cast_bf(const float* __restrict__ X,
                                               short* __restrict__ Xb, int nElem) {
  int idx = blockIdx.x * 256 + threadIdx.x;
  if (idx < nElem) Xb[idx] = f2bf(X[idx]);
}

// ---- staged bf16 MFMA GEMM (m97 structure) + bijective XCD swizzle ----
// BF16OUT: write C as bf16 (for proj, whose only consumer re-quantizes anyway)
template<int BM, bool BF16OUT>
__global__ __launch_bounds__(256) void gemm_st(const short* __restrict__ A,
                                               const short* __restrict__ Bp,
                                               void* __restrict__ Cv,
                                               int M, int N, int K) {
  constexpr int MI = BM / 32;                 // m-fragments per wave
  __shared__ short sA[BM * 64];               // [BM][64] bf16, swizzled
  __shared__ short sB[8 * 128 * 8];           // [kg][n][8] bf16, linear
  int tid = threadIdx.x;
  int lane = tid & 63, wid = tid >> 6;
  int wr = wid >> 1, wc = wid & 1;
  int l15 = lane & 15, l16 = lane >> 4;

  // XCD-aware bijective swizzle (nwg % 8 == 0 for all our grids)
  int nwg = gridDim.x * gridDim.y;
  int lin = blockIdx.x + gridDim.x * blockIdx.y;
  int cpx = nwg >> 3;
  int swz = (lin & 7) * cpx + (lin >> 3);
  int bm = (swz % gridDim.x) * BM, bn = (swz / gridDim.x) * 128;

  f32x4 acc[MI][4] = {};

  int arow = lane >> 3;                       // row within 8-row group
  int acolb = ((lane & 7) ^ arow) * 16;       // inverse-swizzled source byte
  const char* Ag = (const char*)(A + (size_t)bm * K) + acolb;
  const char* Bg = (const char*)(Bp + (size_t)bn * 8);

  for (int k0 = 0; k0 < K; k0 += 64) {
    __syncthreads();
#pragma unroll
    for (int q = 0; q < BM / 32; ++q) {       // stage A: 1KB per inst
      int rbase = (q * 4 + wid) * 8;
      gll16(Ag + ((size_t)(rbase + arow) * K + k0) * 2,
            (char*)sA + rbase * 128);
    }
#pragma unroll
    for (int q = 0; q < 4; ++q) {             // stage B: 1KB per inst
      int c = q * 4 + wid;
      int kg = c >> 1, nh = (c & 1) * 64;
      gll16(Bg + ((size_t)(k0 / 8 + kg) * N * 8 + (size_t)(nh + lane) * 8) * 2,
            (char*)sB + kg * 2048 + nh * 16);
    }
    __syncthreads();

#pragma unroll
    for (int kk = 0; kk < 64; kk += 32) {
      s16x8 a[MI], b[4];
#pragma unroll
      for (int mi = 0; mi < MI; ++mi) {
        int row = wr * (BM / 2) + mi * 16 + l15;
        int kb = ((kk + l16 * 8) * 2) ^ ((row & 7) << 4);   // swizzled read
        a[mi] = *(const s16x8*)((const char*)sA + row * 128 + kb);
      }
#pragma unroll
      for (int ni = 0; ni < 4; ++ni) {
        int n = wc * 64 + ni * 16 + l15;
        int kg = (kk >> 3) + l16;
        b[ni] = *(const s16x8*)((const char*)sB + (kg * 128 + n) * 16);
      }
#pragma unroll
      for (int mi = 0; mi < MI; ++mi)
#pragma unroll
        for (int ni = 0; ni < 4; ++ni)
          acc[mi][ni] = __builtin_amdgcn_mfma_f32_16x16x32_bf16(a[mi], b[ni], acc[mi][ni], 0, 0, 0);
    }
  }
#pragma unroll
  for (int mi = 0; mi < MI; ++mi) {
    int row0 = bm + wr * (BM / 2) + mi * 16 + l16 * 4;
#pragma unroll
    for (int ni = 0; ni < 4; ++ni) {
      int col = bn + wc * 64 + ni * 16 + l15;
#pragma unroll
      for (int r = 0; r < 4; ++r) {
        if constexpr (BF16OUT)
          ((short*)Cv)[(size_t)(row0 + r) * N + col] = f2bf(acc[mi][ni][r]);
        else
          ((float*)Cv)[(size_t)(row0 + r) * N + col] = acc[mi][ni][r];
      }
    }
  }
}

// ---- causal depthwise conv (K=4) + SiLU -> bf16; silu(gate) -> bf16 ----
// proj now bf16
__global__ __launch_bounds__(256) void conv_silu(const short* __restrict__ proj,
                                                 const float* __restrict__ convw,
                                                 short* __restrict__ hsb,
                                                 short* __restrict__ gate_b) {
  int idx = blockIdx.x * 256 + threadIdx.x;   // over L_*I_
  int t = idx >> 11, i = idx & (I_ - 1);
  int col = ((i >> 7) << 8) + 128 + (i & 127);  // head*256 + 128 + (i%128)
  float4 cw = *(const float4*)(convw + i * 4);
  const short* p = proj + (size_t)t * (2 * I_) + col;
  float acc = cw.w * bf2f((unsigned short)p[0]);
  if (t >= 1) acc += cw.z * bf2f((unsigned short)p[-(2 * I_)]);
  if (t >= 2) acc += cw.y * bf2f((unsigned short)p[-(2 * I_) * 2]);
  if (t >= 3) acc += cw.x * bf2f((unsigned short)p[-(2 * I_) * 3]);
  float h = acc / (1.f + __expf(-acc));   // silu
  hsb[idx] = f2bf(h);
  float g = bf2f((unsigned short)p[-128]);  // gate element for channel i
  gate_b[idx] = f2bf(g / (1.f + __expf(-g)));   // silu(gate)
}

// ---- RMSNorms (B, C, ts) + dt = ts@dt_proj + softplus(dt + bias) ----
__global__ __launch_bounds__(256) void norm_dt(const float* __restrict__ sp,
                                               const float* __restrict__ Bw,
                                               const float* __restrict__ Cw,
                                               const float* __restrict__ dtw,
                                               const float* __restrict__ Wdt,
                                               const float* __restrict__ bias,
                                               float* __restrict__ Bo,
                                               float* __restrict__ Co,
                                               float* __restrict__ delta) {
  int lane = threadIdx.x & 63, w = threadIdx.x >> 6;
  int t = blockIdx.x * 4 + w;
  const float* row = sp + (size_t)t * 256;
  float v0 = row[lane], v1 = row[64 + lane], v2 = row[128 + lane], v3 = row[192 + lane];
  float sB = v0 * v0, sC = v1 * v1, sT = v2 * v2 + v3 * v3;
#pragma unroll
  for (int off = 32; off; off >>= 1) {
    sB += __shfl_xor(sB, off);
    sC += __shfl_xor(sC, off);
    sT += __shfl_xor(sT, off);
  }
  float rB = rsqrtf(sB * (1.f / 64) + 1e-6f);
  float rC = rsqrtf(sC * (1.f / 64) + 1e-6f);
  float rT = rsqrtf(sT * (1.f / 128) + 1e-6f);
  Bo[t * 64 + lane] = v0 * rB * Bw[lane];
  Co[t * 64 + lane] = v1 * rC * Cw[lane];
  float t2 = v2 * rT * dtw[lane], t3 = v3 * rT * dtw[64 + lane];
  float p[NH_];
  const float* w0 = Wdt + lane * NH_;
  const float* w1 = Wdt + (64 + lane) * NH_;
#pragma unroll
  for (int h = 0; h < NH_; ++h) p[h] = t2 * w0[h] + t3 * w1[h];
#pragma unroll
  for (int off = 32; off; off >>= 1)
#pragma unroll
    for (int h = 0; h < NH_; ++h) p[h] += __shfl_xor(p[h], off);
  if (lane == 0) {
#pragma unroll
    for (int h = 0; h < NH_; ++h) {
      float x = p[h] + bias[h];
      delta[t * NH_ + h] = (x > 20.f) ? x : log1pf(__expf(x));
    }
  }
}

// ---- per-(chunk, head) delta sums ----
__global__ __launch_bounds__(512) void chunk_sums(const float* __restrict__ delta,
                                                  float* __restrict__ sumd) {
  int t = blockIdx.x * 512 + threadIdx.x;   // NCH_*16 = 1024
  int c = t >> 4, h = t & 15;
  float s = 0.f;
  const float* p = delta + (size_t)c * CT_ * NH_ + h;
#pragma unroll 8
  for (int j = 0; j < CT_; ++j) s += p[(size_t)j * NH_];
  sumd[t] = s;
}

// ======================= chunked selective scan ==========================
// r22-verified: 4ch x 16n; A pre-scaled by log2e; native v_exp; st bf16;
// u-tile staged in LDS.
__device__ __forceinline__ float rdlane(float v, int l) {
  return __builtin_bit_cast(float, __builtin_amdgcn_readlane(__builtin_bit_cast(int, v), l));
}

// ---- phase 1: local scan from zero (state only) ----
__global__ __launch_bounds__(256) void scan1(const short* __restrict__ hs,     // [L+1, I] bf16
                                             const float* __restrict__ Bm,     // [L, N]
                                             const float* __restrict__ delta,  // [L, NH]
                                             const float* __restrict__ A,      // [I, N]
                                             short* __restrict__ st) {         // [NCH][N][I] bf16
  __shared__ float sB[CT_ * 64];              // 8 KB
  __shared__ float su[CT_ * 256];             // 32 KB
  int tid = threadIdx.x;
  int lane = tid & 63, wv = tid >> 6;
  int c0b = blockIdx.x * 256;
  int c0w = c0b + wv * 64;
  int c = lane & 15, q = lane >> 4;
  int chunk = blockIdx.y;
  int t0 = chunk * CT_;
  int head = c0w >> 7;
  int nb = q * 16;
  int ch0 = c0w + c;
  int lu = wv * 64 + c;                       // local u index base

  { const float4* B4 = (const float4*)(Bm + (size_t)t0 * 64);
    float4* S4 = (float4*)sB;
    S4[tid] = B4[tid];
    S4[256 + tid] = B4[256 + tid]; }
  // stage u tile [32][256] bf16 -> f32 (4 coalesced short8 loads/thread)
  { int cc = tid & 31, tt0 = tid >> 5;
#pragma unroll
    for (int r = 0; r < 4; ++r) {
      int tt = r * 8 + tt0;
      s16x8 v = *(const s16x8*)(hs + (size_t)(t0 + tt) * I_ + c0b + cc * 8);
      float* dst = &su[tt * 256 + cc * 8];
      float4 lo = {bf2f((unsigned short)v[0]), bf2f((unsigned short)v[1]),
                   bf2f((unsigned short)v[2]), bf2f((unsigned short)v[3])};
      float4 hi = {bf2f((unsigned short)v[4]), bf2f((unsigned short)v[5]),
                   bf2f((unsigned short)v[6]), bf2f((unsigned short)v[7])};
      *(float4*)dst = lo;
      *(float4*)(dst + 4) = hi;
    } }
  float d_r = delta[(size_t)(t0 + (lane & 31)) * NH_ + head];

  float aL[4][16], s[4][16];
#pragma unroll
  for (int j = 0; j < 4; ++j) {
    const float* Ap = A + (size_t)(ch0 + 16 * j) * 64 + nb;
#pragma unroll
    for (int k4 = 0; k4 < 4; ++k4) {
      float4 av = *(const float4*)(Ap + k4 * 4);
      aL[j][k4*4+0] = av.x * LOG2E; aL[j][k4*4+1] = av.y * LOG2E;
      aL[j][k4*4+2] = av.z * LOG2E; aL[j][k4*4+3] = av.w * LOG2E;
    }
#pragma unroll
    for (int k = 0; k < 16; ++k) s[j][k] = 0.f;
  }
  __syncthreads();

#pragma unroll 1
  for (int t = 0; t < CT_; ++t) {
    float dlt = rdlane(d_r, t);
    const float* ut = &su[t * 256 + lu];
    float du0 = dlt * ut[0], du1 = dlt * ut[16], du2 = dlt * ut[32], du3 = dlt * ut[48];
    const float* bt = &sB[t * 64 + nb];
#pragma unroll
    for (int k4 = 0; k4 < 4; ++k4) {
      float4 b4 = *(const float4*)&bt[k4 * 4];
#pragma unroll
      for (int e = 0; e < 4; ++e) {
        int k = k4 * 4 + e; float bb = (&b4.x)[e];
        s[0][k] = s[0][k] * ex2(dlt * aL[0][k]) + du0 * bb;
        s[1][k] = s[1][k] * ex2(dlt * aL[1][k]) + du1 * bb;
        s[2][k] = s[2][k] * ex2(dlt * aL[2][k]) + du2 * bb;
        s[3][k] = s[3][k] * ex2(dlt * aL[3][k]) + du3 * bb;
      }
    }
  }
  size_t base = ((size_t)chunk << 17) + ch0;
#pragma unroll
  for (int j = 0; j < 4; ++j)
#pragma unroll
    for (int k = 0; k < 16; ++k)
      st[base + ((size_t)(nb + k) << 11) + 16 * j] = f2bf(s[j][k]);
}

// ---- phase 2: register-blocked sequential combine (loads all chunks) ----
__global__ __launch_bounds__(256) void scan2(const float* __restrict__ A,
                                             const float* __restrict__ sumd,  // [NCH*16]
                                             short* __restrict__ st) {        // [NCH][N][I] bf16
  int g = blockIdx.x * 256 + threadIdx.x;    // over N*I = 131072
  int i = g & (I_ - 1), n = g >> 11;
  int h = i >> 7;
  float aL = A[((size_t)i << 6) + n] * LOG2E;
  float loc[NCH_];
#pragma unroll
  for (int c = 0; c < NCH_; ++c)
    loc[c] = bf2f((unsigned short)st[((size_t)c << 17) + g]);
  float s = 0.f;
#pragma unroll
  for (int c = 0; c < NCH_; ++c) {
    float gfac = ex2(aL * sumd[c * 16 + h]);
    float nxt = s * gfac + loc[c];
    st[((size_t)c << 17) + g] = f2bf(s);      // incoming state for chunk c
    s = nxt;
  }
}

// ---- phase 3: recompute with incoming state + y + fused epilogue ----
__global__ __launch_bounds__(256) void scan3(const short* __restrict__ hs,     // [L+1, I] bf16
                                             const float* __restrict__ Bm,     // [L, N]
                                             const float* __restrict__ Cm,     // [L, N]
                                             const float* __restrict__ delta,  // [L, NH]
                                             const float* __restrict__ A,      // [I, N]
                                             const float* __restrict__ Dv,     // [I]
                                             const short* __restrict__ gate_b, // [L, I] bf16
                                             const short* __restrict__ st,     // [NCH][N][I] bf16
                                             short* __restrict__ ybf) {        // [L, I] bf16
  __shared__ float sB[CT_ * 64], sC[CT_ * 64];   // 16 KB
  __shared__ float su[CT_ * 256];                // 32 KB
  int tid = threadIdx.x;
  int lane = tid & 63, wv = tid >> 6;
  int c0b = blockIdx.x * 256;
  int c0w = c0b + wv * 64;
  int c = lane & 15, q = lane >> 4;
  int chunk = blockIdx.y;
  int t0 = chunk * CT_;
  int head = c0w >> 7;
  int nb = q * 16;
  int ch0 = c0w + c;
  int lu = wv * 64 + c;

  { const float4* B4 = (const float4*)(Bm + (size_t)t0 * 64);
    const float4* C4 = (const float4*)(Cm + (size_t)t0 * 64);
    float4* SB4 = (float4*)sB;
    float4* SC4 = (float4*)sC;
    SB4[tid] = B4[tid];       SB4[256 + tid] = B4[256 + tid];
    SC4[tid] = C4[tid];       SC4[256 + tid] = C4[256 + tid]; }
  // stage u tile [32][256] bf16 -> f32
  { int cc = tid & 31, tt0 = tid >> 5;
#pragma unroll
    for (int r = 0; r < 4; ++r) {
      int tt = r * 8 + tt0;
      s16x8 v = *(const s16x8*)(hs + (size_t)(t0 + tt) * I_ + c0b + cc * 8);
      float* dst = &su[tt * 256 + cc * 8];
      float4 lo = {bf2f((unsigned short)v[0]), bf2f((unsigned short)v[1]),
                   bf2f((unsigned short)v[2]), bf2f((unsigned short)v[3])};
      float4 hi = {bf2f((unsigned short)v[4]), bf2f((unsigned short)v[5]),
                   bf2f((unsigned short)v[6]), bf2f((unsigned short)v[7])};
      *(float4*)dst = lo;
      *(float4*)(dst + 4) = hi;
    } }
  float d_r = delta[(size_t)(t0 + (lane & 31)) * NH_ + head];
  float D_own = Dv[c0w + lane];

  float aL[4][16], s[4][16];
#pragma unroll
  for (int j = 0; j < 4; ++j) {
    const float* Ap = A + (size_t)(ch0 + 16 * j) * 64 + nb;
#pragma unroll
    for (int k4 = 0; k4 < 4; ++k4) {
      float4 av = *(const float4*)(Ap + k4 * 4);
      aL[j][k4*4+0] = av.x * LOG2E; aL[j][k4*4+1] = av.y * LOG2E;
      aL[j][k4*4+2] = av.z * LOG2E; aL[j][k4*4+3] = av.w * LOG2E;
    }
  }
  { size_t base = ((size_t)chunk << 17) + ch0;
#pragma unroll
    for (int j = 0; j < 4; ++j)
#pragma unroll
      for (int k = 0; k < 16; ++k)
        s[j][k] = bf2f((unsigned short)st[base + ((size_t)(nb + k) << 11) + 16 * j]);
  }
  __syncthreads();

  const short* gp = gate_b + (size_t)t0 * I_ + c0w + lane;
  short* yp = ybf + (size_t)t0 * I_ + c0w + lane;
  bool b4f = lane & 16, b5f = lane & 32;
#pragma unroll 1
  for (int t = 0; t < CT_; ++t) {
    float gv = bf2f((unsigned short)gp[(size_t)t * I_]);
    float dlt = rdlane(d_r, t);
    const float* ut = &su[t * 256 + lu];
    float du0 = dlt * ut[0], du1 = dlt * ut[16], du2 = dlt * ut[32], du3 = dlt * ut[48];
    float u_own = su[t * 256 + wv * 64 + lane];
    const float* bt = &sB[t * 64 + nb];
    const float* ct = &sC[t * 64 + nb];
    float p0 = 0.f, p1 = 0.f, p2 = 0.f, p3 = 0.f;
#pragma unroll
    for (int k4 = 0; k4 < 4; ++k4) {
      float4 b4 = *(const float4*)&bt[k4 * 4];
      float4 c4 = *(const float4*)&ct[k4 * 4];
#pragma unroll
      for (int e = 0; e < 4; ++e) {
        int k = k4 * 4 + e;
        float bb = (&b4.x)[e], cc = (&c4.x)[e];
        s[0][k] = s[0][k] * ex2(dlt * aL[0][k]) + du0 * bb;  p0 += s[0][k] * cc;
        s[1][k] = s[1][k] * ex2(dlt * aL[1][k]) + du1 * bb;  p1 += s[1][k] * cc;
        s[2][k] = s[2][k] * ex2(dlt * aL[2][k]) + du2 * bb;  p2 += s[2][k] * cc;
        s[3][k] = s[3][k] * ex2(dlt * aL[3][k]) + du3 * bb;  p3 += s[3][k] * cc;
      }
    }
    // reduce over n-quarters; lane (q,c) ends with y for channel c0w+lane
    float sa = b5f ? p0 : p2;
    float sb = b5f ? p1 : p3;
    float qa = (b5f ? p2 : p0) + __shfl_xor(sa, 32);
    float qb = (b5f ? p3 : p1) + __shfl_xor(sb, 32);
    float sc = b4f ? qa : qb;
    float y  = (b4f ? qb : qa) + __shfl_xor(sc, 16);
    y += D_own * u_own;
    yp[(size_t)t * I_] = f2bf(y * gv);
  }
}

extern "C" void kernel_launch(void* const* d_in, const int* in_sizes, int n_in,
                              void* d_out, int out_size, void* d_ws, size_t ws_size,
                              hipStream_t stream) {
  const float* hidden  = (const float*)d_in[0];
  const float* inproj  = (const float*)d_in[1];
  const float* convw   = (const float*)d_in[2];
  const float* bcdtw   = (const float*)d_in[3];
  const float* dtnw    = (const float*)d_in[4];
  const float* Bnw     = (const float*)d_in[5];
  const float* Cnw     = (const float*)d_in[6];
  const float* dtpw    = (const float*)d_in[7];
  const float* dtbias  = (const float*)d_in[8];
  const float* Amat    = (const float*)d_in[9];
  const float* Dvec    = (const float*)d_in[10];
  const float* outproj = (const float*)d_in[11];
  float* out = (float*)d_out;

  char* ws = (char*)d_ws;
  short* inproj_p  = (short*)ws; ws += (size_t)H_ * 2 * I_ * 2;   // 16 MB
  short* bcdt_p    = (short*)ws; ws += (size_t)I_ * 256 * 2;
  short* outproj_p = (short*)ws; ws += (size_t)I_ * H_ * 2;
  short* hid_b     = (short*)ws; ws += (size_t)L_ * H_ * 2;
  short* proj_b    = (short*)ws; ws += (size_t)L_ * 2 * I_ * 2;   // 16 MB bf16
  short* hs_b      = (short*)ws; ws += (size_t)(L_ + 1) * I_ * 2; // +1 pad row
  short* gate_b    = (short*)ws; ws += (size_t)L_ * I_ * 2;       // 8 MB
  float* ssmp      = (float*)ws; ws += (size_t)L_ * 256 * 4;
  float* Bmat      = (float*)ws; ws += (size_t)L_ * NS_ * 4;
  float* Cmat      = (float*)ws; ws += (size_t)L_ * NS_ * 4;
  float* delta     = (float*)ws; ws += (size_t)L_ * NH_ * 4;
  short* y_b       = (short*)ws; ws += (size_t)L_ * I_ * 2;
  float* sumd      = (float*)ws; ws += NCH_ * 16 * 4;
  // chunk-state buffer [NCH][N][I] bf16 = 16 MB: aliases proj_b (same size),
  // dead after conv_silu (gate extracted to gate_b).  Stream-ordered.
  short* sstate    = proj_b;

  pack_w8<<<(H_ * 2 * I_ / 8 + 255) / 256, 256, 0, stream>>>(inproj, inproj_p, H_ * 2 * I_ / 8, 12);
  pack_w8<<<(I_ * 256 / 8 + 255) / 256, 256, 0, stream>>>(bcdtw, bcdt_p, I_ * 256 / 8, 8);
  pack_w8<<<(I_ * H_ / 8 + 255) / 256, 256, 0, stream>>>(outproj, outproj_p, I_ * H_ / 8, 11);
  cast_bf<<<(L_ * H_ + 255) / 256, 256, 0, stream>>>(hidden, hid_b, L_ * H_);

  gemm_st<128, true><<<dim3(L_ / 128, (2 * I_) / 128), 256, 0, stream>>>(hid_b, inproj_p, proj_b, L_, 2 * I_, H_);
  conv_silu<<<(L_ * I_) / 256, 256, 0, stream>>>(proj_b, convw, hs_b, gate_b);
  gemm_st<64, false><<<dim3(L_ / 64, 256 / 128), 256, 0, stream>>>(hs_b, bcdt_p, ssmp, L_, 256, I_);
  norm_dt<<<L_ / 4, 256, 0, stream>>>(ssmp, Bnw, Cnw, dtnw, dtpw, dtbias, Bmat, Cmat, delta);

  chunk_sums<<<(NCH_ * 16) / 512, 512, 0, stream>>>(delta, sumd);
  scan1<<<dim3(I_ / 256, NCH_), 256, 0, stream>>>(hs_b, Bmat, delta, Amat, sstate);
  scan2<<<(I_ * 64) / 256, 256, 0, stream>>>(Amat, sumd, sstate);
  scan3<<<dim3(I_ / 256, NCH_), 256, 0, stream>>>(hs_b, Bmat, Cmat, delta, Amat, Dvec, gate_b, sstate, y_b);

  gemm_st<64, false><<<dim3(L_ / 64, H_ / 128), 256, 0, stream>>>(y_b, outproj_p, out, L_, H_, I_);
}